// Round 9
// baseline (255.559 us; speedup 1.0000x reference)
//
#include <hip/hip_runtime.h>

// BindingFormer fused pipeline for MI355X (gfx950), round 11.
// r10b post-mortem: nt stores REGRESSED (WRITE 66.5->85.7MB, waves stall on
// HBM store drain) and PROJ prefetch exposed stalls (VALUBusy down, time up)
// -> both reverted to r8's proven structure (71us). New lever: the rope
// block (64 of 96 GEMM1 K-cols) is a function of DISCRETE disp = resi[s]-
// resi[d] in {-255..255} x chain-eq -> precompute ROPE_PROJ[512][256] f32
// (512KB, L2-class; row 511 = zeros for cross-chain), same factorization
// that won r7 for rep. Deletes all rope sincos fill (the transcendental 45%
// of feature VALU), 16 of 24 GEMM1 MFMAs; edge_in K=32 (27 geom + 5 zero).

typedef __attribute__((ext_vector_type(8))) short short8;  // 8 x bf16 (4 VGPRs)
typedef __attribute__((ext_vector_type(4))) float f32x4;   // MFMA accumulator

#define TWO_PI 6.283185307179586f
#define E_AB_TOT 131072

// ws layout (bytes)
#define WS_RT    0         // frames: 1024 x 12 f32            = 49152
#define WS_REPB  49152     // rep bf16 1024x256                = 524288
#define WS_W1F   573440    // swizzled W1' 19*16*64*8 bf16     = 311296
#define WS_W2F   884736    // swizzled W2  8*8*64*8 bf16       = 65536
#define WS_PS    950272    // PROJ_S f32 1024x256 (+bias1)     = 1048576
#define WS_PD    1998848   // PROJ_D f32 1024x256              = 1048576
#define WS_ROPE  3047424   // ROPE_PROJ f32 512x256            = 524288

__device__ __forceinline__ unsigned short f2bf(float x){
  unsigned int u = __float_as_uint(x);
  u += 0x7fffu + ((u >> 16) & 1u);            // RTNE
  return (unsigned short)(u >> 16);
}

// pack two f32 -> two bf16 (RTNE) in one u32 via v_perm
__device__ __forceinline__ unsigned int pack_bf16(float lo, float hi){
  unsigned int ul = __float_as_uint(lo), uh = __float_as_uint(hi);
  ul += 0x7fffu + ((ul >> 16) & 1u);
  uh += 0x7fffu + ((uh >> 16) & 1u);
  return __builtin_amdgcn_perm(uh, ul, 0x07060302);  // {uh[31:16], ul[31:16]}
}

// gelu tanh-form == x * sigmoid(2z), z = 0.79788456(x + 0.044715 x^3)
__device__ __forceinline__ float gelu_s(float x){
  float s = x * x;
  float w = x * __builtin_fmaf(-0.1029437f, s, -2.30220847f);
  float e = __builtin_exp2f(w);
  return x * __builtin_amdgcn_rcpf(1.0f + e);
}

// ---------- merged prep: rep MLP (blk 0-127) | frames (128-131) |
//            swz2 (132-147) | swz1 s=3..18 (148-211) | wg1+s0 (212-227) -----
__global__ __launch_bounds__(256) void prep_k(
    const float* __restrict__ emb, const float* __restrict__ ts,
    const float* __restrict__ tf,  const float* __restrict__ w1,
    const float* __restrict__ b1,  const float* __restrict__ w2,
    const float* __restrict__ b2,  unsigned short* __restrict__ repb,
    const float* __restrict__ coords, float* __restrict__ RT,
    const float* __restrict__ wg, const float* __restrict__ w1e,
    unsigned short* __restrict__ w1f,
    const float* __restrict__ w2e, unsigned short* __restrict__ w2f){
  __shared__ float xt[288 * 12];   // rep part; wg1 blocks: 128x16 input slab
  __shared__ float ht[256 * 12];   // rep part; wg1 blocks: 27x16 result
  int blk = blockIdx.x, tid = threadIdx.x;
  if (blk < 128){                   // ---- node MLP, 8 nodes/block ----
    int n0 = blk * 8;
    #pragma unroll
    for (int nd = 0; nd < 8; ++nd)
      xt[tid * 12 + nd] = emb[(n0 + nd) * 256 + tid];
    {
      int nd = tid >> 5, j = tid & 31;
      float ang = TWO_PI * ts[n0 + nd] * tf[j & 15];
      float s, c; __sincosf(ang, &s, &c);
      xt[(256 + j) * 12 + nd] = (j < 16) ? s : c;
    }
    __syncthreads();
    float acc[8];
    float bias1 = b1[tid];
    #pragma unroll
    for (int nd = 0; nd < 8; ++nd) acc[nd] = bias1;
    #pragma unroll 4
    for (int k = 0; k < 288; ++k){
      float w = w1[k * 256 + tid];
      f32x4 xa = *(const f32x4*)&xt[k * 12];
      f32x4 xb = *(const f32x4*)&xt[k * 12 + 4];
      acc[0] += xa[0]*w; acc[1] += xa[1]*w; acc[2] += xa[2]*w; acc[3] += xa[3]*w;
      acc[4] += xb[0]*w; acc[5] += xb[1]*w; acc[6] += xb[2]*w; acc[7] += xb[3]*w;
    }
    #pragma unroll
    for (int nd = 0; nd < 8; ++nd) ht[tid * 12 + nd] = gelu_s(acc[nd]);
    __syncthreads();
    float acc2[8];
    float bias2 = b2[tid];
    #pragma unroll
    for (int nd = 0; nd < 8; ++nd) acc2[nd] = bias2;
    #pragma unroll 4
    for (int k = 0; k < 256; ++k){
      float w = w2[k * 256 + tid];
      f32x4 ha = *(const f32x4*)&ht[k * 12];
      f32x4 hb = *(const f32x4*)&ht[k * 12 + 4];
      acc2[0] += ha[0]*w; acc2[1] += ha[1]*w; acc2[2] += ha[2]*w; acc2[3] += ha[3]*w;
      acc2[4] += hb[0]*w; acc2[5] += hb[1]*w; acc2[6] += hb[2]*w; acc2[7] += hb[3]*w;
    }
    #pragma unroll
    for (int nd = 0; nd < 8; ++nd)
      repb[(n0 + nd) * 256 + tid] = f2bf(acc2[nd] + xt[tid * 12 + nd]);
  } else if (blk < 132){            // ---- frames ----
    int n = (blk - 128) * 256 + tid;
    const float* p = coords + n * 9;
    float ax=p[0],ay=p[1],az=p[2], bx=p[3],by=p[4],bz=p[5], cx=p[6],cy=p[7],cz=p[8];
    float v1x=cx-bx, v1y=cy-by, v1z=cz-bz;
    float v2x=ax-bx, v2y=ay-by, v2z=az-bz;
    float n1 = sqrtf(v1x*v1x+v1y*v1y+v1z*v1z) + 1e-6f;
    float e1x=v1x/n1, e1y=v1y/n1, e1z=v1z/n1;
    float dp = e1x*v2x + e1y*v2y + e1z*v2z;
    float u2x=v2x-e1x*dp, u2y=v2y-e1y*dp, u2z=v2z-e1z*dp;
    float n2 = sqrtf(u2x*u2x+u2y*u2y+u2z*u2z) + 1e-6f;
    float e2x=u2x/n2, e2y=u2y/n2, e2z=u2z/n2;
    float* r = RT + n * 12;
    r[0]=e1x; r[1]=e2x; r[2]=e1y*e2z - e1z*e2y;
    r[3]=e1y; r[4]=e2y; r[5]=e1z*e2x - e1x*e2z;
    r[6]=e1z; r[7]=e2z; r[8]=e1x*e2y - e1y*e2x;
    r[9]=bx;  r[10]=by; r[11]=bz;
  } else if (blk < 148){            // ---- swz2: W2 (256x128) -> frag ----
    int u = (blk - 132) * 4 + (tid >> 6);   // 0..63
    int lane = tid & 63;
    int s = u >> 3, c = u & 7;
    int n  = c * 16 + (lane & 15);
    int kb = s * 32 + (lane >> 4) * 8;
    unsigned short* o = w2f + (((s * 8 + c) * 64) + lane) * 8;
    unsigned short vals[8];
    #pragma unroll
    for (int j = 0; j < 8; ++j)
      vals[j] = f2bf(w2e[(kb + j) * 128 + n]);
    *(uint4*)o = *(const uint4*)vals;
  } else if (blk < 212){            // ---- swz1: W1' rep k-tiles s=3..18 ----
    // K: [0:27 geom (wg1 blocks) | 27:96 zero (rope via ROPE_PROJ table)
    //     | 96:352 rep_src (192:448) | 352:608 rep_dst (448:704)]
    int u = 48 + (blk - 148) * 4 + (tid >> 6);   // 48..303 (s >= 3)
    int lane = tid & 63;
    int s = u >> 4, c = u & 15;
    int n  = c * 16 + (lane & 15);
    int kb = s * 32 + (lane >> 4) * 8;
    unsigned short* o = w1f + (((s * 16 + c) * 64) + lane) * 8;
    unsigned short vals[8];
    for (int j = 0; j < 8; ++j){
      int k = kb + j;            // >= 96 here
      float val;
      if (k < 352)      val = w1e[(192 + k - 96)  * 256 + n];
      else              val = w1e[(448 + k - 352) * 256 + n];
      vals[j] = f2bf(val);
    }
    *(uint4*)o = *(const uint4*)vals;
  } else {                          // ---- wg1 (27x16 window) + w1f s0 tile ----
    int c = blk - 212;              // 0..15 = n-window = s0 tile index
    int n0 = c * 16;
    float* slab = xt;               // 128 x 16 f32 input slab
    float* res  = ht;               // 27 x 16 f32 result
    #pragma unroll
    for (int i = 0; i < 8; ++i){
      int idx = tid + 256 * i;      // idx = r*16 + cc
      slab[idx] = w1e[(idx >> 4) * 256 + n0 + (idx & 15)];
    }
    __syncthreads();
    #pragma unroll
    for (int i = 0; i < 2; ++i){
      int o = tid + 256 * i;        // 432 outputs = 27k x 16n
      if (o < 432){
        int k = o >> 4, cc = o & 15;
        float acc = 0.f;
        for (int j2 = 0; j2 < 128; ++j2)
          acc += wg[k * 128 + j2] * slab[j2 * 16 + cc];
        res[o] = acc;
      }
    }
    __syncthreads();
    if (tid < 64){                  // write w1f s=0 tile c: 27 geom + 5 zero
      int lane = tid;
      int nn = lane & 15;
      int kb = (lane >> 4) * 8;
      unsigned short vals[8];
      #pragma unroll
      for (int j = 0; j < 8; ++j){
        int k = kb + j;
        vals[j] = (k < 27) ? f2bf(res[k * 16 + nn]) : (unsigned short)0;
      }
      *(uint4*)(w1f + ((c * 64) + lane) * 8) = *(const uint4*)vals;
    }
  }
}

// ---------- proj_k: PROJ_S/PROJ_D (blk 0-31) | ROPE_PROJ (blk 32-63) -------
// All tables n-INTERLEAVED per 32-n window: phys = (n&~31)|quad<<3|c<<2|rr
// for logical n = 32w+16c+4quad+rr -> edge_k loads both c-tiles from one
// 64B line. bias1 folded into PROJ_S. ROPE_PROJ[r] = rope(disp_r)@W1_rope,
// disp_r = (r-255)/8; row 511 = zeros (cross-chain edges).
__global__ __launch_bounds__(512) void proj_k(
    const unsigned short* __restrict__ repb,
    const unsigned short* __restrict__ w1f,
    const float* __restrict__ b1e, const float* __restrict__ cf,
    const float* __restrict__ w1e,
    float* __restrict__ ps, float* __restrict__ pd,
    float* __restrict__ ropeP)
{
  __shared__ float feat[16][64];
  int tid = threadIdx.x;
  if (blockIdx.x >= 32){            // ---- ROPE_PROJ: 16 rows/block ----
    int rb = (blockIdx.x - 32) * 16;
    {
      int rl = tid >> 5, j = tid & 31;
      int r = rb + rl;
      float disp = (float)(r - 255) * 0.125f;
      float inv = (r == 511) ? 0.f : 1.f / (fabsf(disp) + 1.f);
      float s, c; __sincosf(TWO_PI * disp * cf[j], &s, &c);
      feat[rl][j]      = s * inv;
      feat[rl][32 + j] = c * inv;
    }
    __syncthreads();
    int n = tid & 255;
    int half = tid >> 8;            // 0,1
    int phys = (n & ~31) | (((n >> 2) & 3) << 3) | (((n >> 4) & 1) << 2) | (n & 3);
    #pragma unroll
    for (int it = 0; it < 8; ++it){
      int rr = it * 2 + half;
      float acc = 0.f;
      for (int j2 = 0; j2 < 64; ++j2)
        acc += feat[rr][j2] * w1e[(128 + j2) * 256 + n];
      ropeP[(rb + rr) * 256 + phys] = acc;
    }
    return;
  }
  int part = blockIdx.x & 1;        // 0 = src (s 3..10), 1 = dst (s 11..18)
  int nt   = blockIdx.x >> 1;       // node tile, 64 nodes
  int w = tid >> 6, lane = tid & 63;
  int c0 = w * 2, lr = lane & 15, quad = lane >> 4;
  int n0g = nt * 64;
  const short8* w1f8 = (const short8*)w1f;
  f32x4 acc[8];
  #pragma unroll
  for (int i = 0; i < 8; ++i) acc[i] = (f32x4){0.f, 0.f, 0.f, 0.f};
  int sb = 3 + part * 8;
  #pragma unroll
  for (int s = 0; s < 8; ++s){
    short8 a0 = w1f8[((sb + s) * 16 + c0 + 0) * 64 + lane];
    short8 a1 = w1f8[((sb + s) * 16 + c0 + 1) * 64 + lane];
    #pragma unroll
    for (int t = 0; t < 4; ++t){
      short8 b = *(const short8*)(repb + (n0g + t * 16 + lr) * 256 + s * 32 + quad * 8);
      acc[t]     = __builtin_amdgcn_mfma_f32_16x16x32_bf16(a0, b, acc[t],     0, 0, 0);
      acc[4 + t] = __builtin_amdgcn_mfma_f32_16x16x32_bf16(a1, b, acc[4 + t], 0, 0, 0);
    }
  }
  float* out = part ? pd : ps;
  #pragma unroll
  for (int c = 0; c < 2; ++c){
    f32x4 add = (f32x4){0.f, 0.f, 0.f, 0.f};
    if (!part) add = *(const f32x4*)(b1e + (c0 + c) * 16 + quad * 4);
    #pragma unroll
    for (int t = 0; t < 4; ++t){
      f32x4 v = acc[c * 4 + t];
      v[0] += add[0]; v[1] += add[1]; v[2] += add[2]; v[3] += add[3];
      *(f32x4*)(out + (n0g + t * 16 + lr) * 256 + w * 32 + quad * 8 + c * 4) = v;
    }
  }
}

// ---------- fused edge kernel: 64 edges/block, 512 thr (8 waves) -----------
// TRANSPOSED: mfma(A=weight frag, B=edge/H row frag) -> D[col=edge, row=n].
// GEMM1 K=32 (geom only); rope + rep contributions gathered from f32 tables
// (ROPE_PROJ / PROJ_S / PROJ_D, all L2-class) in the H epilogue.
__global__ __launch_bounds__(512, 4) void edge_k(
    const float* __restrict__ RT,
    const int* __restrict__ resi, const int* __restrict__ chain,
    const int* __restrict__ gia,  const int* __restrict__ gib,
    const int* __restrict__ pid,
    const unsigned short* __restrict__ w1f, const unsigned short* __restrict__ w2f,
    const float* __restrict__ ps, const float* __restrict__ pd,
    const float* __restrict__ ropeP,
    const float* __restrict__ bias2,
    float* __restrict__ outp)
{
  // phase1: edge_in 64 x 64 B (32 bf16, aliased at smem front);
  // phase2: H 64 x 512 B XOR-swizzled ((row&7)<<4)
  __shared__ __align__(16) char smem[32768];
  __shared__ __align__(16) float rtbuf[128][12];   // 64 src rows, 64 dst rows
  __shared__ int lsrc[64];
  __shared__ int ldst[64];
  __shared__ int ridx[64];          // rope table row (511 = cross-chain zero)

  int tid = threadIdx.x;
  int e0  = blockIdx.x * 64;

  if (tid < 64){                    // indices + rope row
    int e = e0 + tid, s_, d_;
    if (e < E_AB_TOT){ s_ = gia[e]; d_ = gib[e]; }
    else {
      int i = e - E_AB_TOT;
      int b = i >> 10, w_ = i & 1023;
      s_ = pid[b * 32 + (w_ >> 5)];
      d_ = pid[b * 32 + (w_ & 31)];
    }
    lsrc[tid] = s_; ldst[tid] = d_;
    ridx[tid] = (chain[s_] == chain[d_]) ? (resi[s_] - resi[d_] + 255) : 511;
  } else if (tid < 192){            // RT staging: 128 rows x 48 B, vectorized
    int r  = tid - 64;              // 0..127 : 0..63 = src rows, 64..127 = dst
    int e  = e0 + (r & 63);
    int node;
    if (e < E_AB_TOT){ node = (r < 64) ? gia[e] : gib[e]; }
    else {
      int i = e - E_AB_TOT;
      int b = i >> 10, w_ = i & 1023;
      node = (r < 64) ? pid[b * 32 + (w_ >> 5)] : pid[b * 32 + (w_ & 31)];
    }
    const f32x4* p = (const f32x4*)(RT + node * 12);
    f32x4* q = (f32x4*)(&rtbuf[r][0]);
    q[0] = p[0]; q[1] = p[1]; q[2] = p[2];
  }
  __syncthreads();

  int w    = tid >> 6, lane = tid & 63;
  int c0   = w * 2;                 // GEMM1: 2 n-tiles per wave
  int lr   = lane & 15;             // edge within e-tile
  int quad = lane >> 4, qoff = quad * 16;

  // ---- feature fill: cols 0..26 geom + 27..31 zero (rope via table) ----
  {
    // rbf: 64 edges x 15 centers
    #pragma unroll
    for (int it = 0; it < 2; ++it){
      int v = it * 512 + tid, ed = v >> 4, c = v & 15;
      float tx = rtbuf[64 + ed][9]  - rtbuf[ed][9];
      float ty = rtbuf[64 + ed][10] - rtbuf[ed][10];
      float tz = rtbuf[64 + ed][11] - rtbuf[ed][11];
      float dist = sqrtf(tx*tx + ty*ty + tz*tz + 1e-6f);
      if (c < 15){
        float z = (dist - (float)c * (20.f / 14.f)) * (15.f / 20.f);
        ((unsigned short*)(smem + ed * 64))[c] = f2bf(__expf(-0.5f * z * z));
      }
    }
    // relrot (9) + local (3): cols 15..26
    #pragma unroll
    for (int it = 0; it < 2; ++it){
      int v = it * 512 + tid, ed = v >> 4, cc = v & 15;
      if (cc < 12){
        const float* Rs = &rtbuf[ed][0];
        const float* Rd = &rtbuf[64 + ed][0];
        float val;
        if (cc < 9){
          int a  = (cc >= 6) ? 2 : ((cc >= 3) ? 1 : 0);
          int b_ = cc - 3 * a;
          val = Rs[a]*Rd[b_] + Rs[3+a]*Rd[3+b_] + Rs[6+a]*Rd[6+b_];
        } else {
          int k = cc - 9;
          float tx = Rd[9]-Rs[9], ty = Rd[10]-Rs[10], tz = Rd[11]-Rs[11];
          float dist = sqrtf(tx*tx + ty*ty + tz*tz + 1e-6f);
          val = (Rs[k]*tx + Rs[3+k]*ty + Rs[6+k]*tz) / (dist + 1.f);
        }
        ((unsigned short*)(smem + ed * 64))[15 + cc] = f2bf(val);
      }
    }
    // zeros: cols 27..31 (weights also zero, but NaN*0 = NaN — must zero)
    {
      int ed = tid >> 3, c8 = tid & 7;
      if (c8 < 5) ((unsigned short*)(smem + ed * 64))[27 + c8] = 0;
    }
  }
  __syncthreads();

  // ---- GEMM1 (transposed): D[n][e] = W1_geom^T x edge_in^T, K=32 ----
  f32x4 acc[8];                     // [c*4 + etile]
  #pragma unroll
  for (int i = 0; i < 8; ++i) acc[i] = (f32x4){0.f, 0.f, 0.f, 0.f};
  const short8* w1f8 = (const short8*)w1f;
  {
    short8 a0 = w1f8[(c0 + 0) * 64 + lane];
    short8 a1 = w1f8[(c0 + 1) * 64 + lane];
    short8 be0 = *(const short8*)(smem + ( 0 + lr) * 64 + qoff);
    short8 be1 = *(const short8*)(smem + (16 + lr) * 64 + qoff);
    short8 be2 = *(const short8*)(smem + (32 + lr) * 64 + qoff);
    short8 be3 = *(const short8*)(smem + (48 + lr) * 64 + qoff);
    acc[0] = __builtin_amdgcn_mfma_f32_16x16x32_bf16(a0, be0, acc[0], 0, 0, 0);
    acc[1] = __builtin_amdgcn_mfma_f32_16x16x32_bf16(a0, be1, acc[1], 0, 0, 0);
    acc[2] = __builtin_amdgcn_mfma_f32_16x16x32_bf16(a0, be2, acc[2], 0, 0, 0);
    acc[3] = __builtin_amdgcn_mfma_f32_16x16x32_bf16(a0, be3, acc[3], 0, 0, 0);
    acc[4] = __builtin_amdgcn_mfma_f32_16x16x32_bf16(a1, be0, acc[4], 0, 0, 0);
    acc[5] = __builtin_amdgcn_mfma_f32_16x16x32_bf16(a1, be1, acc[5], 0, 0, 0);
    acc[6] = __builtin_amdgcn_mfma_f32_16x16x32_bf16(a1, be2, acc[6], 0, 0, 0);
    acc[7] = __builtin_amdgcn_mfma_f32_16x16x32_bf16(a1, be3, acc[7], 0, 0, 0);
  }

  // gather offsets into interleaved tables (one 64B line per table per lane)
  int offS[4], offD[4], offR[4];
  #pragma unroll
  for (int t = 0; t < 4; ++t){
    int base = w * 32 + quad * 8;
    offS[t] = lsrc[t * 16 + lr] * 256 + base;
    offD[t] = ldst[t * 16 + lr] * 256 + base;
    offR[t] = ridx[t * 16 + lr] * 256 + base;
  }
  __syncthreads();   // edge_in reads done; alias LDS as H (64 x 512 B, swz)

  // H[e][n] = gelu(D + PS[src] + PD[dst] + ROPE[disp])   (b1 inside PS)
  {
    char* Hb = smem;
    #pragma unroll
    for (int c = 0; c < 2; ++c){
      f32x4 pv[4], qv[4], rv[4];
      #pragma unroll
      for (int t = 0; t < 4; ++t){
        pv[t] = *(const f32x4*)(ps    + offS[t] + c * 4);
        qv[t] = *(const f32x4*)(pd    + offD[t] + c * 4);
        rv[t] = *(const f32x4*)(ropeP + offR[t] + c * 4);
      }
      int n = (c0 + c) * 16 + quad * 4;
      #pragma unroll
      for (int t = 0; t < 4; ++t){
        int e = t * 16 + lr;
        f32x4 s4 = acc[c * 4 + t];
        float v0 = gelu_s(s4[0] + pv[t][0] + qv[t][0] + rv[t][0]);
        float v1 = gelu_s(s4[1] + pv[t][1] + qv[t][1] + rv[t][1]);
        float v2 = gelu_s(s4[2] + pv[t][2] + qv[t][2] + rv[t][2]);
        float v3 = gelu_s(s4[3] + pv[t][3] + qv[t][3] + rv[t][3]);
        uint2 p; p.x = pack_bf16(v0, v1); p.y = pack_bf16(v2, v3);
        *(uint2*)(Hb + ((e * 512 + n * 2) ^ ((e & 7) << 4))) = p;
      }
    }
  }
  __syncthreads();

  // ---- GEMM2 (transposed): wave owns n-tiles {c2,c2+1} x e-tiles {eb,eb+16}
  int c2 = (w & 3) * 2;
  int eb = (w >> 2) * 32;
  int hx = (lr & 7) << 4;           // row-dependent XOR (rows differ by 16)
  f32x4 acc2[4];                    // [c*2 + t]
  #pragma unroll
  for (int i = 0; i < 4; ++i) acc2[i] = (f32x4){0.f, 0.f, 0.f, 0.f};
  const short8* w2f8 = (const short8*)w2f;
  #pragma unroll
  for (int s = 0; s < 8; ++s){
    short8 aa0 = w2f8[(s * 8 + c2 + 0) * 64 + lane];
    short8 aa1 = w2f8[(s * 8 + c2 + 1) * 64 + lane];
    short8 h0 = *(const short8*)(smem + (((eb +  0 + lr) * 512 + s * 64 + qoff) ^ hx));
    short8 h1 = *(const short8*)(smem + (((eb + 16 + lr) * 512 + s * 64 + qoff) ^ hx));
    acc2[0] = __builtin_amdgcn_mfma_f32_16x16x32_bf16(aa0, h0, acc2[0], 0, 0, 0);
    acc2[1] = __builtin_amdgcn_mfma_f32_16x16x32_bf16(aa0, h1, acc2[1], 0, 0, 0);
    acc2[2] = __builtin_amdgcn_mfma_f32_16x16x32_bf16(aa1, h0, acc2[2], 0, 0, 0);
    acc2[3] = __builtin_amdgcn_mfma_f32_16x16x32_bf16(aa1, h1, acc2[3], 0, 0, 0);
  }

  // output: lane writes 2 x f32x4 per edge (n0, n0+16) -> wave covers full
  // 128-B line of each of its 32 edge rows (plain stores — nt regressed)
  {
    int n0 = c2 * 16 + quad * 4;
    f32x4 bz0 = *(const f32x4*)(bias2 + n0);
    f32x4 bz1 = *(const f32x4*)(bias2 + n0 + 16);
    float* og = outp + (size_t)e0 * 128;
    #pragma unroll
    for (int t = 0; t < 2; ++t){
      int e = eb + t * 16 + lr;
      f32x4 v0, v1;
      v0[0] = acc2[t][0] + bz0[0]; v0[1] = acc2[t][1] + bz0[1];
      v0[2] = acc2[t][2] + bz0[2]; v0[3] = acc2[t][3] + bz0[3];
      v1[0] = acc2[2 + t][0] + bz1[0]; v1[1] = acc2[2 + t][1] + bz1[1];
      v1[2] = acc2[2 + t][2] + bz1[2]; v1[3] = acc2[2 + t][3] + bz1[3];
      *(f32x4*)(og + (size_t)e * 128 + n0)      = v0;
      *(f32x4*)(og + (size_t)e * 128 + n0 + 16) = v1;
    }
  }
}

extern "C" void kernel_launch(void* const* d_in, const int* in_sizes, int n_in,
                              void* d_out, int out_size, void* d_ws, size_t ws_size,
                              hipStream_t stream) {
  const float* emb    = (const float*)d_in[0];
  const float* ts     = (const float*)d_in[1];
  const float* coords = (const float*)d_in[2];
  const float* tf     = (const float*)d_in[3];
  const float* cf     = (const float*)d_in[4];
  const float* w1r    = (const float*)d_in[5];
  const float* b1r    = (const float*)d_in[6];
  const float* w2r    = (const float*)d_in[7];
  const float* b2r    = (const float*)d_in[8];
  const float* wg     = (const float*)d_in[9];
  const float* w1e    = (const float*)d_in[10];
  const float* b1e    = (const float*)d_in[11];
  const float* w2e    = (const float*)d_in[12];
  const float* b2e    = (const float*)d_in[13];
  const int* resi     = (const int*)d_in[14];
  const int* chain    = (const int*)d_in[15];
  const int* gia      = (const int*)d_in[16];
  const int* gib      = (const int*)d_in[17];
  const int* pid      = (const int*)d_in[18];

  char* ws = (char*)d_ws;
  float* RT            = (float*)(ws + WS_RT);
  unsigned short* REPB = (unsigned short*)(ws + WS_REPB);
  unsigned short* W1F  = (unsigned short*)(ws + WS_W1F);
  unsigned short* W2F  = (unsigned short*)(ws + WS_W2F);
  float* PS            = (float*)(ws + WS_PS);
  float* PD            = (float*)(ws + WS_PD);
  float* ROPEP         = (float*)(ws + WS_ROPE);
  float* outp          = (float*)d_out;

  hipLaunchKernelGGL(prep_k, dim3(228), dim3(256), 0, stream,
                     emb, ts, tf, w1r, b1r, w2r, b2r, REPB,
                     coords, RT, wg, w1e, W1F, w2e, W2F);
  hipLaunchKernelGGL(proj_k, dim3(64), dim3(512), 0, stream,
                     REPB, W1F, b1e, cf, w1e, PS, PD, ROPEP);
  hipLaunchKernelGGL(edge_k, dim3(2080), dim3(512), 0, stream,
                     RT, resi, chain, gia, gib, pid, W1F, W2F, PS, PD, ROPEP,
                     b2e, outp);
}

// Round 10
// 202.790 us; speedup vs baseline: 1.2602x; 1.2602x over previous
//
#include <hip/hip_runtime.h>

// BindingFormer fused pipeline for MI355X (gfx950), round 12.
// r11 post-mortem: ROPE_PROJ table REGRESSED (FETCH 9.6->16.5MB; rope
// sincos was TRANS-pipe & hidden; table added a 3rd random-gather stream).
// Factorization only wins when it REMOVES traffic (rep: -133MB) not adds.
// r12 = proven-best recombination: r9d edge body (interleaved PROJ 64B-line
// gathers, H 512-swz, rope in-kernel) at (512,4) with LDS padded to 44032
// to FORCE 3 blocks/CU (4 blocks = L2 write thrash, WRITE 104MB; 3 = 66.5).
// prep_k node MLP: 4 nodes/block x 256 blocks (was 8x128 = half GPU idle).

typedef __attribute__((ext_vector_type(8))) short short8;  // 8 x bf16 (4 VGPRs)
typedef __attribute__((ext_vector_type(4))) float f32x4;   // MFMA accumulator

#define TWO_PI 6.283185307179586f
#define E_AB_TOT 131072

// ws layout (bytes)
#define WS_RT    0         // frames: 1024 x 12 f32            = 49152
#define WS_REPB  49152     // rep bf16 1024x256                = 524288
#define WS_W1F   573440    // swizzled W1' 19*16*64*8 bf16     = 311296
#define WS_W2F   884736    // swizzled W2  8*8*64*8 bf16       = 65536
#define WS_PS    950272    // PROJ_S f32 1024x256 (+bias1)     = 1048576
#define WS_PD    1998848   // PROJ_D f32 1024x256              = 1048576

__device__ __forceinline__ unsigned short f2bf(float x){
  unsigned int u = __float_as_uint(x);
  u += 0x7fffu + ((u >> 16) & 1u);            // RTNE
  return (unsigned short)(u >> 16);
}

// pack two f32 -> two bf16 (RTNE) in one u32 via v_perm
__device__ __forceinline__ unsigned int pack_bf16(float lo, float hi){
  unsigned int ul = __float_as_uint(lo), uh = __float_as_uint(hi);
  ul += 0x7fffu + ((ul >> 16) & 1u);
  uh += 0x7fffu + ((uh >> 16) & 1u);
  return __builtin_amdgcn_perm(uh, ul, 0x07060302);  // {uh[31:16], ul[31:16]}
}

// gelu tanh-form == x * sigmoid(2z), z = 0.79788456(x + 0.044715 x^3)
__device__ __forceinline__ float gelu_s(float x){
  float s = x * x;
  float w = x * __builtin_fmaf(-0.1029437f, s, -2.30220847f);
  float e = __builtin_exp2f(w);
  return x * __builtin_amdgcn_rcpf(1.0f + e);
}

// ---------- merged prep: rep MLP (blk 0-255, 4 nodes each) | frames
//  (256-259) | swz2 (260-275) | swz1 s>=1 (276-347) | wg1+s0 (348-363) ------
__global__ __launch_bounds__(256) void prep_k(
    const float* __restrict__ emb, const float* __restrict__ ts,
    const float* __restrict__ tf,  const float* __restrict__ w1,
    const float* __restrict__ b1,  const float* __restrict__ w2,
    const float* __restrict__ b2,  unsigned short* __restrict__ repb,
    const float* __restrict__ coords, float* __restrict__ RT,
    const float* __restrict__ wg, const float* __restrict__ w1e,
    unsigned short* __restrict__ w1f,
    const float* __restrict__ w2e, unsigned short* __restrict__ w2f){
  __shared__ float xt[288 * 12];   // rep part; wg1 blocks: 128x16 input slab
  __shared__ float ht[256 * 12];   // rep part; wg1 blocks: 27x16 result
  int blk = blockIdx.x, tid = threadIdx.x;
  if (blk < 256){                   // ---- node MLP, 4 nodes/block ----
    int n0 = blk * 4;
    #pragma unroll
    for (int nd = 0; nd < 4; ++nd)
      xt[tid * 12 + nd] = emb[(n0 + nd) * 256 + tid];
    if (tid < 128){
      int nd = tid >> 5, j = tid & 31;
      float ang = TWO_PI * ts[n0 + nd] * tf[j & 15];
      float s, c; __sincosf(ang, &s, &c);
      xt[(256 + j) * 12 + nd] = (j < 16) ? s : c;
    }
    __syncthreads();
    float acc[4];
    float bias1 = b1[tid];
    #pragma unroll
    for (int nd = 0; nd < 4; ++nd) acc[nd] = bias1;
    #pragma unroll 8
    for (int k = 0; k < 288; ++k){
      float w = w1[k * 256 + tid];
      f32x4 xa = *(const f32x4*)&xt[k * 12];
      acc[0] += xa[0]*w; acc[1] += xa[1]*w; acc[2] += xa[2]*w; acc[3] += xa[3]*w;
    }
    #pragma unroll
    for (int nd = 0; nd < 4; ++nd) ht[tid * 12 + nd] = gelu_s(acc[nd]);
    __syncthreads();
    float acc2[4];
    float bias2 = b2[tid];
    #pragma unroll
    for (int nd = 0; nd < 4; ++nd) acc2[nd] = bias2;
    #pragma unroll 8
    for (int k = 0; k < 256; ++k){
      float w = w2[k * 256 + tid];
      f32x4 ha = *(const f32x4*)&ht[k * 12];
      acc2[0] += ha[0]*w; acc2[1] += ha[1]*w; acc2[2] += ha[2]*w; acc2[3] += ha[3]*w;
    }
    #pragma unroll
    for (int nd = 0; nd < 4; ++nd)
      repb[(n0 + nd) * 256 + tid] = f2bf(acc2[nd] + xt[tid * 12 + nd]);
  } else if (blk < 260){            // ---- frames ----
    int n = (blk - 256) * 256 + tid;
    const float* p = coords + n * 9;
    float ax=p[0],ay=p[1],az=p[2], bx=p[3],by=p[4],bz=p[5], cx=p[6],cy=p[7],cz=p[8];
    float v1x=cx-bx, v1y=cy-by, v1z=cz-bz;
    float v2x=ax-bx, v2y=ay-by, v2z=az-bz;
    float n1 = sqrtf(v1x*v1x+v1y*v1y+v1z*v1z) + 1e-6f;
    float e1x=v1x/n1, e1y=v1y/n1, e1z=v1z/n1;
    float dp = e1x*v2x + e1y*v2y + e1z*v2z;
    float u2x=v2x-e1x*dp, u2y=v2y-e1y*dp, u2z=v2z-e1z*dp;
    float n2 = sqrtf(u2x*u2x+u2y*u2y+u2z*u2z) + 1e-6f;
    float e2x=u2x/n2, e2y=u2y/n2, e2z=u2z/n2;
    float* r = RT + n * 12;
    r[0]=e1x; r[1]=e2x; r[2]=e1y*e2z - e1z*e2y;
    r[3]=e1y; r[4]=e2y; r[5]=e1z*e2x - e1x*e2z;
    r[6]=e1z; r[7]=e2z; r[8]=e1x*e2y - e1y*e2x;
    r[9]=bx;  r[10]=by; r[11]=bz;
  } else if (blk < 276){            // ---- swz2: W2 (256x128) -> frag ----
    int u = (blk - 260) * 4 + (tid >> 6);   // 0..63
    int lane = tid & 63;
    int s = u >> 3, c = u & 7;
    int n  = c * 16 + (lane & 15);
    int kb = s * 32 + (lane >> 4) * 8;
    unsigned short* o = w2f + (((s * 8 + c) * 64) + lane) * 8;
    unsigned short vals[8];
    #pragma unroll
    for (int j = 0; j < 8; ++j)
      vals[j] = f2bf(w2e[(kb + j) * 128 + n]);
    *(uint4*)o = *(const uint4*)vals;
  } else if (blk < 348){            // ---- swz1: W1' k-tiles s>=1 ----
    // K: [0:27 geom (wg1 blocks) | 27:91 rope (w1e 128:192) | 91:96 zero
    //     | 96:352 rep_src (192:448) | 352:608 rep_dst (448:704)]
    int u = 16 + (blk - 276) * 4 + (tid >> 6);   // 16..303 (s >= 1)
    int lane = tid & 63;
    int s = u >> 4, c = u & 15;
    int n  = c * 16 + (lane & 15);
    int kb = s * 32 + (lane >> 4) * 8;
    unsigned short* o = w1f + (((s * 16 + c) * 64) + lane) * 8;
    unsigned short vals[8];
    for (int j = 0; j < 8; ++j){
      int k = kb + j;            // >= 32 here
      float val;
      if (k < 91)       val = w1e[(128 + k - 27)  * 256 + n];
      else if (k < 96)  val = 0.f;
      else if (k < 352) val = w1e[(192 + k - 96)  * 256 + n];
      else              val = w1e[(448 + k - 352) * 256 + n];
      vals[j] = f2bf(val);
    }
    *(uint4*)o = *(const uint4*)vals;
  } else {                          // ---- wg1 (27x16 window) + w1f s0 tile ----
    int c = blk - 348;              // 0..15 = n-window = s0 tile index
    int n0 = c * 16;
    float* slab = xt;               // 128 x 16 f32 input slab
    float* res  = ht;               // 27 x 16 f32 result
    #pragma unroll
    for (int i = 0; i < 8; ++i){
      int idx = tid + 256 * i;      // idx = r*16 + cc
      slab[idx] = w1e[(idx >> 4) * 256 + n0 + (idx & 15)];
    }
    __syncthreads();
    #pragma unroll
    for (int i = 0; i < 2; ++i){
      int o = tid + 256 * i;        // 432 outputs = 27k x 16n
      if (o < 432){
        int k = o >> 4, cc = o & 15;
        float acc = 0.f;
        for (int j2 = 0; j2 < 128; ++j2)
          acc += wg[k * 128 + j2] * slab[j2 * 16 + cc];
        res[o] = acc;
      }
    }
    __syncthreads();
    if (tid < 64){                  // write w1f s=0 tile c (k<27 geom,
      int lane = tid;               //  k in [27,32) = first 5 rope rows)
      int nn = lane & 15;
      int kb = (lane >> 4) * 8;
      unsigned short vals[8];
      #pragma unroll
      for (int j = 0; j < 8; ++j){
        int k = kb + j;
        float val = (k < 27) ? res[k * 16 + nn]
                             : w1e[(128 + k - 27) * 256 + n0 + nn];
        vals[j] = f2bf(val);
      }
      *(uint4*)(w1f + ((c * 64) + lane) * 8) = *(const uint4*)vals;
    }
  }
}

// ---------- proj_k: PROJ_S/PROJ_D = REP @ W1_{src,dst}, n-interleaved ------
// PROJ layout per 32-n window: [node][w*32 + quad*8 + c*4 + r] holds logical
// n = (w*2+c)*16 + quad*4 + r, so edge_k loads both c-tiles from one 64B
// line. bias1 folded into PROJ_S.
__global__ __launch_bounds__(512) void proj_k(
    const unsigned short* __restrict__ repb,
    const unsigned short* __restrict__ w1f,
    const float* __restrict__ b1e,
    float* __restrict__ ps, float* __restrict__ pd)
{
  int part = blockIdx.x & 1;        // 0 = src (s 3..10), 1 = dst (s 11..18)
  int nt   = blockIdx.x >> 1;       // node tile, 64 nodes
  int tid  = threadIdx.x, w = tid >> 6, lane = tid & 63;
  int c0 = w * 2, lr = lane & 15, quad = lane >> 4;
  int n0g = nt * 64;
  const short8* w1f8 = (const short8*)w1f;
  f32x4 acc[8];
  #pragma unroll
  for (int i = 0; i < 8; ++i) acc[i] = (f32x4){0.f, 0.f, 0.f, 0.f};
  int sb = 3 + part * 8;
  #pragma unroll
  for (int s = 0; s < 8; ++s){
    short8 a0 = w1f8[((sb + s) * 16 + c0 + 0) * 64 + lane];
    short8 a1 = w1f8[((sb + s) * 16 + c0 + 1) * 64 + lane];
    #pragma unroll
    for (int t = 0; t < 4; ++t){
      short8 b = *(const short8*)(repb + (n0g + t * 16 + lr) * 256 + s * 32 + quad * 8);
      acc[t]     = __builtin_amdgcn_mfma_f32_16x16x32_bf16(a0, b, acc[t],     0, 0, 0);
      acc[4 + t] = __builtin_amdgcn_mfma_f32_16x16x32_bf16(a1, b, acc[4 + t], 0, 0, 0);
    }
  }
  float* out = part ? pd : ps;
  #pragma unroll
  for (int c = 0; c < 2; ++c){
    f32x4 add = (f32x4){0.f, 0.f, 0.f, 0.f};
    if (!part) add = *(const f32x4*)(b1e + (c0 + c) * 16 + quad * 4);
    #pragma unroll
    for (int t = 0; t < 4; ++t){
      f32x4 v = acc[c * 4 + t];
      v[0] += add[0]; v[1] += add[1]; v[2] += add[2]; v[3] += add[3];
      *(f32x4*)(out + (n0g + t * 16 + lr) * 256 + w * 32 + quad * 8 + c * 4) = v;
    }
  }
}

// ---------- fused edge kernel: 64 edges/block, 512 thr (8 waves) -----------
// TRANSPOSED: mfma(A=weight frag, B=edge/H row frag) -> D[col=edge, row=n].
// smem 36864 (32768 used + 4096 pad) -> LDS 44032 -> 3 blocks/CU (4 blocks
// thrashes L2: WRITE 104MB; 3 blocks = clean 66.5MB, measured r8 vs r9d).
__global__ __launch_bounds__(512, 4) void edge_k(
    const float* __restrict__ RT,  const float* __restrict__ cf,
    const int* __restrict__ resi, const int* __restrict__ chain,
    const int* __restrict__ gia,  const int* __restrict__ gib,
    const int* __restrict__ pid,
    const unsigned short* __restrict__ w1f, const unsigned short* __restrict__ w2f,
    const float* __restrict__ ps, const float* __restrict__ pd,
    const float* __restrict__ bias2,
    float* __restrict__ outp)
{
  // phase1: edge_in 64 x 208 B (96 bf16 + pad); phase2 alias: H 64 x 512 B swz
  __shared__ __align__(16) char smem[36864];       // 32768 used + 4096 pad
  __shared__ __align__(16) float rtbuf[128][12];   // 64 src rows, 64 dst rows
  __shared__ float scD[64];                         // disp
  __shared__ float scI[64];                         // rope scale (chain mask)
  __shared__ int lsrc[64];
  __shared__ int ldst[64];

  int tid = threadIdx.x;
  int e0  = blockIdx.x * 64;

  if (tid < 64){                    // indices + per-edge scalars
    int e = e0 + tid, s_, d_;
    if (e < E_AB_TOT){ s_ = gia[e]; d_ = gib[e]; }
    else {
      int i = e - E_AB_TOT;
      int b = i >> 10, w_ = i & 1023;
      s_ = pid[b * 32 + (w_ >> 5)];
      d_ = pid[b * 32 + (w_ & 31)];
    }
    lsrc[tid] = s_; ldst[tid] = d_;
    float disp = ((float)resi[s_] - (float)resi[d_]) * 0.125f;
    scD[tid] = disp;
    scI[tid] = (chain[s_] == chain[d_]) ? 1.f / (fabsf(disp) + 1.f) : 0.f;
  } else if (tid < 192){            // RT staging: 128 rows x 48 B, vectorized
    int r  = tid - 64;              // 0..127 : 0..63 = src rows, 64..127 = dst
    int e  = e0 + (r & 63);
    int node;
    if (e < E_AB_TOT){ node = (r < 64) ? gia[e] : gib[e]; }
    else {
      int i = e - E_AB_TOT;
      int b = i >> 10, w_ = i & 1023;
      node = (r < 64) ? pid[b * 32 + (w_ >> 5)] : pid[b * 32 + (w_ & 31)];
    }
    const f32x4* p = (const f32x4*)(RT + node * 12);
    f32x4* q = (f32x4*)(&rtbuf[r][0]);
    q[0] = p[0]; q[1] = p[1]; q[2] = p[2];
  }
  __syncthreads();

  int w    = tid >> 6, lane = tid & 63;
  int c0   = w * 2;                 // GEMM1: 2 n-tiles per wave
  int lr   = lane & 15;             // edge within e-tile
  int quad = lane >> 4, qoff = quad * 16;

  // ---- divergence-free feature fill (cols 0..95 of edge_in) ----
  {
    // rope: 2048 (edge, freq) pairs, one sincos fills sin+cos cols
    #pragma unroll
    for (int it = 0; it < 4; ++it){
      int v = it * 512 + tid, ed = v >> 5, j = v & 31;
      float ang = TWO_PI * scD[ed] * cf[j];
      float s, c; __sincosf(ang, &s, &c);
      float inv = scI[ed];
      unsigned short* row = (unsigned short*)(smem + ed * 208);
      row[27 + j] = f2bf(s * inv);
      row[59 + j] = f2bf(c * inv);
    }
    // rbf: 64 edges x 15 centers (c==15 lanes idle)
    #pragma unroll
    for (int it = 0; it < 2; ++it){
      int v = it * 512 + tid, ed = v >> 4, c = v & 15;
      float tx = rtbuf[64 + ed][9]  - rtbuf[ed][9];
      float ty = rtbuf[64 + ed][10] - rtbuf[ed][10];
      float tz = rtbuf[64 + ed][11] - rtbuf[ed][11];
      float dist = sqrtf(tx*tx + ty*ty + tz*tz + 1e-6f);
      if (c < 15){
        float z = (dist - (float)c * (20.f / 14.f)) * (15.f / 20.f);
        ((unsigned short*)(smem + ed * 208))[c] = f2bf(__expf(-0.5f * z * z));
      }
    }
    // relrot (9) + local (3): cols 15..26
    #pragma unroll
    for (int it = 0; it < 2; ++it){
      int v = it * 512 + tid, ed = v >> 4, cc = v & 15;
      if (cc < 12){
        const float* Rs = &rtbuf[ed][0];
        const float* Rd = &rtbuf[64 + ed][0];
        float val;
        if (cc < 9){
          int a  = (cc >= 6) ? 2 : ((cc >= 3) ? 1 : 0);
          int b_ = cc - 3 * a;
          val = Rs[a]*Rd[b_] + Rs[3+a]*Rd[3+b_] + Rs[6+a]*Rd[6+b_];
        } else {
          int k = cc - 9;
          float tx = Rd[9]-Rs[9], ty = Rd[10]-Rs[10], tz = Rd[11]-Rs[11];
          float dist = sqrtf(tx*tx + ty*ty + tz*tz + 1e-6f);
          val = (Rs[k]*tx + Rs[3+k]*ty + Rs[6+k]*tz) / (dist + 1.f);
        }
        ((unsigned short*)(smem + ed * 208))[15 + cc] = f2bf(val);
      }
    }
    // zeros: cols 91..98 (96..98 are pad, harmless)
    {
      int ed = tid >> 3, c8 = tid & 7;
      ((unsigned short*)(smem + ed * 208))[91 + c8] = 0;
    }
  }
  __syncthreads();

  // ---- GEMM1 (transposed): D[n][e] = W1_feat^T x edge_in^T, K=96 ----
  f32x4 acc[8];                     // [c*4 + etile]
  #pragma unroll
  for (int i = 0; i < 8; ++i) acc[i] = (f32x4){0.f, 0.f, 0.f, 0.f};
  const short8* w1f8 = (const short8*)w1f;

  #pragma unroll
  for (int s = 0; s < 3; ++s){
    short8 a0 = w1f8[(s * 16 + c0 + 0) * 64 + lane];
    short8 a1 = w1f8[(s * 16 + c0 + 1) * 64 + lane];
    short8 be0 = *(const short8*)(smem + ( 0 + lr) * 208 + s * 64 + qoff);
    short8 be1 = *(const short8*)(smem + (16 + lr) * 208 + s * 64 + qoff);
    short8 be2 = *(const short8*)(smem + (32 + lr) * 208 + s * 64 + qoff);
    short8 be3 = *(const short8*)(smem + (48 + lr) * 208 + s * 64 + qoff);
    acc[0] = __builtin_amdgcn_mfma_f32_16x16x32_bf16(a0, be0, acc[0], 0, 0, 0);
    acc[1] = __builtin_amdgcn_mfma_f32_16x16x32_bf16(a0, be1, acc[1], 0, 0, 0);
    acc[2] = __builtin_amdgcn_mfma_f32_16x16x32_bf16(a0, be2, acc[2], 0, 0, 0);
    acc[3] = __builtin_amdgcn_mfma_f32_16x16x32_bf16(a0, be3, acc[3], 0, 0, 0);
    acc[4] = __builtin_amdgcn_mfma_f32_16x16x32_bf16(a1, be0, acc[4], 0, 0, 0);
    acc[5] = __builtin_amdgcn_mfma_f32_16x16x32_bf16(a1, be1, acc[5], 0, 0, 0);
    acc[6] = __builtin_amdgcn_mfma_f32_16x16x32_bf16(a1, be2, acc[6], 0, 0, 0);
    acc[7] = __builtin_amdgcn_mfma_f32_16x16x32_bf16(a1, be3, acc[7], 0, 0, 0);
  }

  // 32-bit gather offsets into interleaved PROJ tables (one 64B line each)
  int offS[4], offD[4];
  #pragma unroll
  for (int t = 0; t < 4; ++t){
    offS[t] = lsrc[t * 16 + lr] * 256 + w * 32 + quad * 8;
    offD[t] = ldst[t * 16 + lr] * 256 + w * 32 + quad * 8;
  }
  __syncthreads();   // edge_in reads done; alias LDS as H (64 x 512 B, swz)

  // H[e][n] = gelu(D + PROJ_S[src][n'] + PROJ_D[dst][n'])  (b1 inside PROJ_S)
  {
    char* Hb = smem;
    #pragma unroll
    for (int c = 0; c < 2; ++c){
      f32x4 pv[4], qv[4];
      #pragma unroll
      for (int t = 0; t < 4; ++t){
        pv[t] = *(const f32x4*)(ps + offS[t] + c * 4);
        qv[t] = *(const f32x4*)(pd + offD[t] + c * 4);
      }
      int n = (c0 + c) * 16 + quad * 4;
      #pragma unroll
      for (int t = 0; t < 4; ++t){
        int e = t * 16 + lr;
        f32x4 s4 = acc[c * 4 + t];
        float v0 = gelu_s(s4[0] + pv[t][0] + qv[t][0]);
        float v1 = gelu_s(s4[1] + pv[t][1] + qv[t][1]);
        float v2 = gelu_s(s4[2] + pv[t][2] + qv[t][2]);
        float v3 = gelu_s(s4[3] + pv[t][3] + qv[t][3]);
        uint2 p; p.x = pack_bf16(v0, v1); p.y = pack_bf16(v2, v3);
        *(uint2*)(Hb + ((e * 512 + n * 2) ^ ((e & 7) << 4))) = p;
      }
    }
  }
  __syncthreads();

  // ---- GEMM2 (transposed): wave owns n-tiles {c2,c2+1} x e-tiles {eb,eb+16}
  int c2 = (w & 3) * 2;
  int eb = (w >> 2) * 32;
  int hx = (lr & 7) << 4;           // row-dependent XOR (rows differ by 16)
  f32x4 acc2[4];                    // [c*2 + t]
  #pragma unroll
  for (int i = 0; i < 4; ++i) acc2[i] = (f32x4){0.f, 0.f, 0.f, 0.f};
  const short8* w2f8 = (const short8*)w2f;
  #pragma unroll
  for (int s = 0; s < 8; ++s){
    short8 aa0 = w2f8[(s * 8 + c2 + 0) * 64 + lane];
    short8 aa1 = w2f8[(s * 8 + c2 + 1) * 64 + lane];
    short8 h0 = *(const short8*)(smem + (((eb +  0 + lr) * 512 + s * 64 + qoff) ^ hx));
    short8 h1 = *(const short8*)(smem + (((eb + 16 + lr) * 512 + s * 64 + qoff) ^ hx));
    acc2[0] = __builtin_amdgcn_mfma_f32_16x16x32_bf16(aa0, h0, acc2[0], 0, 0, 0);
    acc2[1] = __builtin_amdgcn_mfma_f32_16x16x32_bf16(aa0, h1, acc2[1], 0, 0, 0);
    acc2[2] = __builtin_amdgcn_mfma_f32_16x16x32_bf16(aa1, h0, acc2[2], 0, 0, 0);
    acc2[3] = __builtin_amdgcn_mfma_f32_16x16x32_bf16(aa1, h1, acc2[3], 0, 0, 0);
  }

  // output: lane writes 2 x f32x4 per edge (n0, n0+16) -> wave covers full
  // 128-B line of each of its 32 edge rows (plain stores)
  {
    int n0 = c2 * 16 + quad * 4;
    f32x4 bz0 = *(const f32x4*)(bias2 + n0);
    f32x4 bz1 = *(const f32x4*)(bias2 + n0 + 16);
    float* og = outp + (size_t)e0 * 128;
    #pragma unroll
    for (int t = 0; t < 2; ++t){
      int e = eb + t * 16 + lr;
      f32x4 v0, v1;
      v0[0] = acc2[t][0] + bz0[0]; v0[1] = acc2[t][1] + bz0[1];
      v0[2] = acc2[t][2] + bz0[2]; v0[3] = acc2[t][3] + bz0[3];
      v1[0] = acc2[2 + t][0] + bz1[0]; v1[1] = acc2[2 + t][1] + bz1[1];
      v1[2] = acc2[2 + t][2] + bz1[2]; v1[3] = acc2[2 + t][3] + bz1[3];
      *(f32x4*)(og + (size_t)e * 128 + n0)      = v0;
      *(f32x4*)(og + (size_t)e * 128 + n0 + 16) = v1;
    }
  }
}

extern "C" void kernel_launch(void* const* d_in, const int* in_sizes, int n_in,
                              void* d_out, int out_size, void* d_ws, size_t ws_size,
                              hipStream_t stream) {
  const float* emb    = (const float*)d_in[0];
  const float* ts     = (const float*)d_in[1];
  const float* coords = (const float*)d_in[2];
  const float* tf     = (const float*)d_in[3];
  const float* cf     = (const float*)d_in[4];
  const float* w1r    = (const float*)d_in[5];
  const float* b1r    = (const float*)d_in[6];
  const float* w2r    = (const float*)d_in[7];
  const float* b2r    = (const float*)d_in[8];
  const float* wg     = (const float*)d_in[9];
  const float* w1e    = (const float*)d_in[10];
  const float* b1e    = (const float*)d_in[11];
  const float* w2e    = (const float*)d_in[12];
  const float* b2e    = (const float*)d_in[13];
  const int* resi     = (const int*)d_in[14];
  const int* chain    = (const int*)d_in[15];
  const int* gia      = (const int*)d_in[16];
  const int* gib      = (const int*)d_in[17];
  const int* pid      = (const int*)d_in[18];

  char* ws = (char*)d_ws;
  float* RT            = (float*)(ws + WS_RT);
  unsigned short* REPB = (unsigned short*)(ws + WS_REPB);
  unsigned short* W1F  = (unsigned short*)(ws + WS_W1F);
  unsigned short* W2F  = (unsigned short*)(ws + WS_W2F);
  float* PS            = (float*)(ws + WS_PS);
  float* PD            = (float*)(ws + WS_PD);
  float* outp          = (float*)d_out;

  hipLaunchKernelGGL(prep_k, dim3(364), dim3(256), 0, stream,
                     emb, ts, tf, w1r, b1r, w2r, b2r, REPB,
                     coords, RT, wg, w1e, W1F, w2e, W2F);
  hipLaunchKernelGGL(proj_k, dim3(32), dim3(512), 0, stream,
                     REPB, W1F, b1e, PS, PD);
  hipLaunchKernelGGL(edge_k, dim3(2080), dim3(512), 0, stream,
                     RT, cf, resi, chain, gia, gib, pid, W1F, W2F, PS, PD,
                     b2e, outp);
}

// Round 11
// 192.643 us; speedup vs baseline: 1.3266x; 1.0527x over previous
//
#include <hip/hip_runtime.h>

// BindingFormer fused pipeline for MI355X (gfx950), round 13.
// r12 post-mortem: total 202.8 (best). edge_k r9d-body (76.3) is ~5us WORSE
// than r8's body (71.4) at identical WRITE/FETCH/occupancy -> interleaved
// PROJ + XOR bought nothing; reverted to r8 verbatim. X = total-edge dropped
// 147->126 from prep re-blocking alone -> node-MLP serial-VALU loop is a
// major X component. r13: node MLP via MFMA (new mlp_k, 285 MFLOP -> ~5us,
// same verified fragment/epilogue patterns as proj_k/edge_k GEMM2); prep_k
// swizzles w1r/w2r frags and drops the serial MLP blocks.

typedef __attribute__((ext_vector_type(8))) short short8;  // 8 x bf16 (4 VGPRs)
typedef __attribute__((ext_vector_type(4))) float f32x4;   // MFMA accumulator

#define TWO_PI 6.283185307179586f
#define E_AB_TOT 131072

// ws layout (bytes)
#define WS_RT    0         // frames: 1024 x 12 f32            = 49152
#define WS_REPB  49152     // rep bf16 1024x256                = 524288
#define WS_W1F   573440    // swizzled W1' 19*16*64*8 bf16     = 311296
#define WS_W2F   884736    // swizzled W2  8*8*64*8 bf16       = 65536
#define WS_PS    950272    // PROJ_S f32 1024x256 (+bias1)     = 1048576
#define WS_PD    1998848   // PROJ_D f32 1024x256              = 1048576
#define WS_W1RF  3047424   // swizzled W1_rep 9*16*64*8 bf16   = 147456
#define WS_W2RF  3194880   // swizzled W2_rep 8*16*64*8 bf16   = 131072

__device__ __forceinline__ unsigned short f2bf(float x){
  unsigned int u = __float_as_uint(x);
  u += 0x7fffu + ((u >> 16) & 1u);            // RTNE
  return (unsigned short)(u >> 16);
}

// pack two f32 -> two bf16 (RTNE) in one u32 via v_perm
__device__ __forceinline__ unsigned int pack_bf16(float lo, float hi){
  unsigned int ul = __float_as_uint(lo), uh = __float_as_uint(hi);
  ul += 0x7fffu + ((ul >> 16) & 1u);
  uh += 0x7fffu + ((uh >> 16) & 1u);
  return __builtin_amdgcn_perm(uh, ul, 0x07060302);  // {uh[31:16], ul[31:16]}
}

// gelu tanh-form == x * sigmoid(2z), z = 0.79788456(x + 0.044715 x^3)
__device__ __forceinline__ float gelu_s(float x){
  float s = x * x;
  float w = x * __builtin_fmaf(-0.1029437f, s, -2.30220847f);
  float e = __builtin_exp2f(w);
  return x * __builtin_amdgcn_rcpf(1.0f + e);
}

// ---------- prep: frames (0-3) | swz2 (4-19) | swz1 s>=1 (20-91) |
//            wg1+s0 (92-107) | swz w1r (108-143) | swz w2r (144-175) --------
__global__ __launch_bounds__(256) void prep_k(
    const float* __restrict__ coords, float* __restrict__ RT,
    const float* __restrict__ wg, const float* __restrict__ w1e,
    unsigned short* __restrict__ w1f,
    const float* __restrict__ w2e, unsigned short* __restrict__ w2f,
    const float* __restrict__ w1r, unsigned short* __restrict__ w1rf,
    const float* __restrict__ w2r, unsigned short* __restrict__ w2rf){
  __shared__ float xt[288 * 12];   // wg1 blocks: 128x16 input slab
  __shared__ float ht[256 * 12];   // wg1 blocks: 27x16 result
  int blk = blockIdx.x, tid = threadIdx.x;
  if (blk < 4){                     // ---- frames ----
    int n = blk * 256 + tid;
    const float* p = coords + n * 9;
    float ax=p[0],ay=p[1],az=p[2], bx=p[3],by=p[4],bz=p[5], cx=p[6],cy=p[7],cz=p[8];
    float v1x=cx-bx, v1y=cy-by, v1z=cz-bz;
    float v2x=ax-bx, v2y=ay-by, v2z=az-bz;
    float n1 = sqrtf(v1x*v1x+v1y*v1y+v1z*v1z) + 1e-6f;
    float e1x=v1x/n1, e1y=v1y/n1, e1z=v1z/n1;
    float dp = e1x*v2x + e1y*v2y + e1z*v2z;
    float u2x=v2x-e1x*dp, u2y=v2y-e1y*dp, u2z=v2z-e1z*dp;
    float n2 = sqrtf(u2x*u2x+u2y*u2y+u2z*u2z) + 1e-6f;
    float e2x=u2x/n2, e2y=u2y/n2, e2z=u2z/n2;
    float* r = RT + n * 12;
    r[0]=e1x; r[1]=e2x; r[2]=e1y*e2z - e1z*e2y;
    r[3]=e1y; r[4]=e2y; r[5]=e1z*e2x - e1x*e2z;
    r[6]=e1z; r[7]=e2z; r[8]=e1x*e2y - e1y*e2x;
    r[9]=bx;  r[10]=by; r[11]=bz;
  } else if (blk < 20){             // ---- swz2: W2 edge (256x128) -> frag ----
    int u = (blk - 4) * 4 + (tid >> 6);     // 0..63
    int lane = tid & 63;
    int s = u >> 3, c = u & 7;
    int n  = c * 16 + (lane & 15);
    int kb = s * 32 + (lane >> 4) * 8;
    unsigned short* o = w2f + (((s * 8 + c) * 64) + lane) * 8;
    unsigned short vals[8];
    #pragma unroll
    for (int j = 0; j < 8; ++j)
      vals[j] = f2bf(w2e[(kb + j) * 128 + n]);
    *(uint4*)o = *(const uint4*)vals;
  } else if (blk < 92){             // ---- swz1: W1' edge k-tiles s>=1 ----
    // K: [0:27 geom (wg1 blocks) | 27:91 rope (w1e 128:192) | 91:96 zero
    //     | 96:352 rep_src (192:448) | 352:608 rep_dst (448:704)]
    int u = 16 + (blk - 20) * 4 + (tid >> 6);    // 16..303 (s >= 1)
    int lane = tid & 63;
    int s = u >> 4, c = u & 15;
    int n  = c * 16 + (lane & 15);
    int kb = s * 32 + (lane >> 4) * 8;
    unsigned short* o = w1f + (((s * 16 + c) * 64) + lane) * 8;
    unsigned short vals[8];
    for (int j = 0; j < 8; ++j){
      int k = kb + j;            // >= 32 here
      float val;
      if (k < 91)       val = w1e[(128 + k - 27)  * 256 + n];
      else if (k < 96)  val = 0.f;
      else if (k < 352) val = w1e[(192 + k - 96)  * 256 + n];
      else              val = w1e[(448 + k - 352) * 256 + n];
      vals[j] = f2bf(val);
    }
    *(uint4*)o = *(const uint4*)vals;
  } else if (blk < 108){            // ---- wg1 (27x16 window) + w1f s0 tile ----
    int c = blk - 92;               // 0..15 = n-window = s0 tile index
    int n0 = c * 16;
    float* slab = xt;               // 128 x 16 f32 input slab
    float* res  = ht;               // 27 x 16 f32 result
    #pragma unroll
    for (int i = 0; i < 8; ++i){
      int idx = tid + 256 * i;      // idx = r*16 + cc
      slab[idx] = w1e[(idx >> 4) * 256 + n0 + (idx & 15)];
    }
    __syncthreads();
    #pragma unroll
    for (int i = 0; i < 2; ++i){
      int o = tid + 256 * i;        // 432 outputs = 27k x 16n
      if (o < 432){
        int k = o >> 4, cc = o & 15;
        float acc = 0.f;
        for (int j2 = 0; j2 < 128; ++j2)
          acc += wg[k * 128 + j2] * slab[j2 * 16 + cc];
        res[o] = acc;
      }
    }
    __syncthreads();
    if (tid < 64){                  // write w1f s=0 tile c (k<27 geom,
      int lane = tid;               //  k in [27,32) = first 5 rope rows)
      int nn = lane & 15;
      int kb = (lane >> 4) * 8;
      unsigned short vals[8];
      #pragma unroll
      for (int j = 0; j < 8; ++j){
        int k = kb + j;
        float val = (k < 27) ? res[k * 16 + nn]
                             : w1e[(128 + k - 27) * 256 + n0 + nn];
        vals[j] = f2bf(val);
      }
      *(uint4*)(w1f + ((c * 64) + lane) * 8) = *(const uint4*)vals;
    }
  } else if (blk < 144){            // ---- swz w1r (288x256) -> frag ----
    int u = (blk - 108) * 4 + (tid >> 6);   // 0..143: s = u>>4 (0..8), c = u&15
    int lane = tid & 63;
    int s = u >> 4, c = u & 15;
    int n  = c * 16 + (lane & 15);
    int kb = s * 32 + (lane >> 4) * 8;
    unsigned short* o = w1rf + (((s * 16 + c) * 64) + lane) * 8;
    unsigned short vals[8];
    #pragma unroll
    for (int j = 0; j < 8; ++j)
      vals[j] = f2bf(w1r[(kb + j) * 256 + n]);
    *(uint4*)o = *(const uint4*)vals;
  } else {                          // ---- swz w2r (256x256) -> frag ----
    int u = (blk - 144) * 4 + (tid >> 6);   // 0..127: s = u>>4 (0..7), c = u&15
    int lane = tid & 63;
    int s = u >> 4, c = u & 15;
    int n  = c * 16 + (lane & 15);
    int kb = s * 32 + (lane >> 4) * 8;
    unsigned short* o = w2rf + (((s * 16 + c) * 64) + lane) * 8;
    unsigned short vals[8];
    #pragma unroll
    for (int j = 0; j < 8; ++j)
      vals[j] = f2bf(w2r[(kb + j) * 256 + n]);
    *(uint4*)o = *(const uint4*)vals;
  }
}

// ---------- mlp_k: node MLP via MFMA. 32 nodes/block, 512 thr (8 waves) ----
// X[32 x 288] bf16 in LDS (stride 592B, 2-way conflicts = free); GEMM1 K=288
// -> gelu -> H1[32 x 256] bf16 (512B stride + XOR swz) -> GEMM2 K=256 ->
// + b2 + emb residual -> repb. Per wave: 2 n-tiles x 2 node-tiles.
__global__ __launch_bounds__(512) void mlp_k(
    const float* __restrict__ emb, const float* __restrict__ ts,
    const float* __restrict__ tf,
    const unsigned short* __restrict__ w1rf, const float* __restrict__ b1r,
    const unsigned short* __restrict__ w2rf, const float* __restrict__ b2r,
    unsigned short* __restrict__ repb)
{
  __shared__ __align__(16) char X[32 * 592];    // 18944 B
  __shared__ __align__(16) char H1[32 * 512];   // 16384 B
  int tid = threadIdx.x;
  int n0g = blockIdx.x * 32;

  // ---- fill X: emb cols 0..255 (bf16x4 stores) ----
  #pragma unroll
  for (int i = 0; i < 4; ++i){
    int idx = tid + 512 * i;        // 2048 = 32 rows x 64 col-groups
    int row = idx >> 6, g = idx & 63;
    f32x4 e = *(const f32x4*)(emb + (n0g + row) * 256 + g * 4);
    uint2 p; p.x = pack_bf16(e[0], e[1]); p.y = pack_bf16(e[2], e[3]);
    *(uint2*)(X + row * 592 + g * 8) = p;
  }
  // te cols 256..287: sin(2pi ts tf[j]) at 256+j, cos at 272+j
  {
    int nd = tid >> 4, j = tid & 15;
    float ang = TWO_PI * ts[n0g + nd] * tf[j];
    float s, c; __sincosf(ang, &s, &c);
    *(unsigned short*)(X + nd * 592 + 512 + 2 * j) = f2bf(s);
    *(unsigned short*)(X + nd * 592 + 544 + 2 * j) = f2bf(c);
  }
  __syncthreads();

  int w = tid >> 6, lane = tid & 63;
  int c0 = w * 2, lr = lane & 15, quad = lane >> 4, qoff = quad * 16;

  // ---- GEMM1: D[n][node] = W1r^T x X^T, K=288 (9 k-tiles) ----
  f32x4 acc[4];                     // [c*2 + t]
  #pragma unroll
  for (int i = 0; i < 4; ++i) acc[i] = (f32x4){0.f, 0.f, 0.f, 0.f};
  const short8* w1rf8 = (const short8*)w1rf;
  #pragma unroll
  for (int s = 0; s < 9; ++s){
    short8 a0 = w1rf8[(s * 16 + c0 + 0) * 64 + lane];
    short8 a1 = w1rf8[(s * 16 + c0 + 1) * 64 + lane];
    short8 b0 = *(const short8*)(X + ( 0 + lr) * 592 + s * 64 + qoff);
    short8 b1 = *(const short8*)(X + (16 + lr) * 592 + s * 64 + qoff);
    acc[0] = __builtin_amdgcn_mfma_f32_16x16x32_bf16(a0, b0, acc[0], 0, 0, 0);
    acc[1] = __builtin_amdgcn_mfma_f32_16x16x32_bf16(a0, b1, acc[1], 0, 0, 0);
    acc[2] = __builtin_amdgcn_mfma_f32_16x16x32_bf16(a1, b0, acc[2], 0, 0, 0);
    acc[3] = __builtin_amdgcn_mfma_f32_16x16x32_bf16(a1, b1, acc[3], 0, 0, 0);
  }

  // H1[node][n] = gelu(D + b1r[n])
  #pragma unroll
  for (int c = 0; c < 2; ++c){
    int n = (c0 + c) * 16 + quad * 4;
    f32x4 bz = *(const f32x4*)(b1r + n);
    #pragma unroll
    for (int t = 0; t < 2; ++t){
      int node = t * 16 + lr;
      f32x4 s4 = acc[c * 2 + t];
      float v0 = gelu_s(s4[0] + bz[0]);
      float v1 = gelu_s(s4[1] + bz[1]);
      float v2 = gelu_s(s4[2] + bz[2]);
      float v3 = gelu_s(s4[3] + bz[3]);
      uint2 p; p.x = pack_bf16(v0, v1); p.y = pack_bf16(v2, v3);
      *(uint2*)(H1 + ((node * 512 + n * 2) ^ ((node & 7) << 4))) = p;
    }
  }
  __syncthreads();

  // ---- GEMM2: D[n][node] = W2r^T x H1^T, K=256 (8 k-tiles) ----
  f32x4 acc2[4];
  #pragma unroll
  for (int i = 0; i < 4; ++i) acc2[i] = (f32x4){0.f, 0.f, 0.f, 0.f};
  const short8* w2rf8 = (const short8*)w2rf;
  int hx = (lr & 7) << 4;
  #pragma unroll
  for (int s = 0; s < 8; ++s){
    short8 a0 = w2rf8[(s * 16 + c0 + 0) * 64 + lane];
    short8 a1 = w2rf8[(s * 16 + c0 + 1) * 64 + lane];
    short8 b0 = *(const short8*)(H1 + ((( 0 + lr) * 512 + s * 64 + qoff) ^ hx));
    short8 b1 = *(const short8*)(H1 + (((16 + lr) * 512 + s * 64 + qoff) ^ hx));
    acc2[0] = __builtin_amdgcn_mfma_f32_16x16x32_bf16(a0, b0, acc2[0], 0, 0, 0);
    acc2[1] = __builtin_amdgcn_mfma_f32_16x16x32_bf16(a0, b1, acc2[1], 0, 0, 0);
    acc2[2] = __builtin_amdgcn_mfma_f32_16x16x32_bf16(a1, b0, acc2[2], 0, 0, 0);
    acc2[3] = __builtin_amdgcn_mfma_f32_16x16x32_bf16(a1, b1, acc2[3], 0, 0, 0);
  }

  // repb[node][n] = bf16(D + b2r[n] + emb[node][n])
  #pragma unroll
  for (int c = 0; c < 2; ++c){
    int n = (c0 + c) * 16 + quad * 4;
    f32x4 bz = *(const f32x4*)(b2r + n);
    #pragma unroll
    for (int t = 0; t < 2; ++t){
      int node = t * 16 + lr;
      f32x4 e = *(const f32x4*)(emb + (n0g + node) * 256 + n);
      f32x4 s4 = acc2[c * 2 + t];
      uint2 p;
      p.x = pack_bf16(s4[0] + bz[0] + e[0], s4[1] + bz[1] + e[1]);
      p.y = pack_bf16(s4[2] + bz[2] + e[2], s4[3] + bz[3] + e[3]);
      *(uint2*)(repb + (n0g + node) * 256 + n) = p;
    }
  }
}

// ---------- proj_k: PROJ_S/PROJ_D = REP @ W1_{src,dst} (r8 verbatim) -------
// Plain layout [node][n]; bias1 folded into PROJ_S.
__global__ __launch_bounds__(512) void proj_k(
    const unsigned short* __restrict__ repb,
    const unsigned short* __restrict__ w1f,
    const float* __restrict__ b1e,
    float* __restrict__ ps, float* __restrict__ pd)
{
  int part = blockIdx.x & 1;        // 0 = src (s 3..10), 1 = dst (s 11..18)
  int nt   = blockIdx.x >> 1;       // node tile, 64 nodes
  int tid  = threadIdx.x, w = tid >> 6, lane = tid & 63;
  int c0 = w * 2, lr = lane & 15, quad = lane >> 4;
  int n0g = nt * 64;
  const short8* w1f8 = (const short8*)w1f;
  f32x4 acc[8];
  #pragma unroll
  for (int i = 0; i < 8; ++i) acc[i] = (f32x4){0.f, 0.f, 0.f, 0.f};
  int sb = 3 + part * 8;
  #pragma unroll
  for (int s = 0; s < 8; ++s){
    short8 a0 = w1f8[((sb + s) * 16 + c0 + 0) * 64 + lane];
    short8 a1 = w1f8[((sb + s) * 16 + c0 + 1) * 64 + lane];
    #pragma unroll
    for (int t = 0; t < 4; ++t){
      short8 b = *(const short8*)(repb + (n0g + t * 16 + lr) * 256 + s * 32 + quad * 8);
      acc[t]     = __builtin_amdgcn_mfma_f32_16x16x32_bf16(a0, b, acc[t],     0, 0, 0);
      acc[4 + t] = __builtin_amdgcn_mfma_f32_16x16x32_bf16(a1, b, acc[4 + t], 0, 0, 0);
    }
  }
  float* out = part ? pd : ps;
  #pragma unroll
  for (int c = 0; c < 2; ++c){
    int n = (c0 + c) * 16 + quad * 4;
    f32x4 add = (f32x4){0.f, 0.f, 0.f, 0.f};
    if (!part) add = *(const f32x4*)(b1e + n);
    #pragma unroll
    for (int t = 0; t < 4; ++t){
      f32x4 v = acc[c * 4 + t];
      v[0] += add[0]; v[1] += add[1]; v[2] += add[2]; v[3] += add[3];
      *(f32x4*)(out + (n0g + t * 16 + lr) * 256 + n) = v;
    }
  }
}

// ---------- fused edge kernel (r8 verbatim: 71.4us measured) ---------------
// 64 edges/block, 512 thr; H stride 560 (conflict-free); plain PROJ gathers
// in the H epilogue; LDS 43008 -> 3 blocks/CU (clean-write regime).
__global__ __launch_bounds__(512, 4) void edge_k(
    const float* __restrict__ RT,  const float* __restrict__ cf,
    const int* __restrict__ resi, const int* __restrict__ chain,
    const int* __restrict__ gia,  const int* __restrict__ gib,
    const int* __restrict__ pid,
    const unsigned short* __restrict__ w1f, const unsigned short* __restrict__ w2f,
    const float* __restrict__ ps, const float* __restrict__ pd,
    const float* __restrict__ bias2,
    float* __restrict__ outp)
{
  // phase1: edge_in 64 x 208 B (96 bf16 + pad); phase2 alias: H 64 x 560 B
  __shared__ __align__(16) char smem[35840];
  __shared__ __align__(16) float rtbuf[128][12];   // 64 src rows, 64 dst rows
  __shared__ float scD[64];                         // disp
  __shared__ float scI[64];                         // rope scale (chain mask)
  __shared__ int lsrc[64];
  __shared__ int ldst[64];

  int tid = threadIdx.x;
  int e0  = blockIdx.x * 64;

  if (tid < 64){                    // indices + per-edge scalars
    int e = e0 + tid, s_, d_;
    if (e < E_AB_TOT){ s_ = gia[e]; d_ = gib[e]; }
    else {
      int i = e - E_AB_TOT;
      int b = i >> 10, w_ = i & 1023;
      s_ = pid[b * 32 + (w_ >> 5)];
      d_ = pid[b * 32 + (w_ & 31)];
    }
    lsrc[tid] = s_; ldst[tid] = d_;
    float disp = ((float)resi[s_] - (float)resi[d_]) * 0.125f;
    scD[tid] = disp;
    scI[tid] = (chain[s_] == chain[d_]) ? 1.f / (fabsf(disp) + 1.f) : 0.f;
  } else if (tid < 192){            // RT staging: 128 rows x 48 B, vectorized
    int r  = tid - 64;              // 0..127 : 0..63 = src rows, 64..127 = dst
    int e  = e0 + (r & 63);
    int node;
    if (e < E_AB_TOT){ node = (r < 64) ? gia[e] : gib[e]; }
    else {
      int i = e - E_AB_TOT;
      int b = i >> 10, w_ = i & 1023;
      node = (r < 64) ? pid[b * 32 + (w_ >> 5)] : pid[b * 32 + (w_ & 31)];
    }
    const f32x4* p = (const f32x4*)(RT + node * 12);
    f32x4* q = (f32x4*)(&rtbuf[r][0]);
    q[0] = p[0]; q[1] = p[1]; q[2] = p[2];
  }
  __syncthreads();

  // ---- divergence-free feature fill (cols 0..95 of edge_in) ----
  {
    // rope: 2048 (edge, freq) pairs, one sincos fills sin+cos cols
    #pragma unroll
    for (int it = 0; it < 4; ++it){
      int v = it * 512 + tid, ed = v >> 5, j = v & 31;
      float ang = TWO_PI * scD[ed] * cf[j];
      float s, c; __sincosf(ang, &s, &c);
      float inv = scI[ed];
      unsigned short* row = (unsigned short*)(smem + ed * 208);
      row[27 + j] = f2bf(s * inv);
      row[59 + j] = f2bf(c * inv);
    }
    // rbf: 64 edges x 15 centers (c==15 lanes idle)
    #pragma unroll
    for (int it = 0; it < 2; ++it){
      int v = it * 512 + tid, ed = v >> 4, c = v & 15;
      float tx = rtbuf[64 + ed][9]  - rtbuf[ed][9];
      float ty = rtbuf[64 + ed][10] - rtbuf[ed][10];
      float tz = rtbuf[64 + ed][11] - rtbuf[ed][11];
      float dist = sqrtf(tx*tx + ty*ty + tz*tz + 1e-6f);
      if (c < 15){
        float z = (dist - (float)c * (20.f / 14.f)) * (15.f / 20.f);
        ((unsigned short*)(smem + ed * 208))[c] = f2bf(__expf(-0.5f * z * z));
      }
    }
    // relrot (9) + local (3): cols 15..26
    #pragma unroll
    for (int it = 0; it < 2; ++it){
      int v = it * 512 + tid, ed = v >> 4, cc = v & 15;
      if (cc < 12){
        const float* Rs = &rtbuf[ed][0];
        const float* Rd = &rtbuf[64 + ed][0];
        float val;
        if (cc < 9){
          int a  = (cc >= 6) ? 2 : ((cc >= 3) ? 1 : 0);
          int b_ = cc - 3 * a;
          val = Rs[a]*Rd[b_] + Rs[3+a]*Rd[3+b_] + Rs[6+a]*Rd[6+b_];
        } else {
          int k = cc - 9;
          float tx = Rd[9]-Rs[9], ty = Rd[10]-Rs[10], tz = Rd[11]-Rs[11];
          float dist = sqrtf(tx*tx + ty*ty + tz*tz + 1e-6f);
          val = (Rs[k]*tx + Rs[3+k]*ty + Rs[6+k]*tz) / (dist + 1.f);
        }
        ((unsigned short*)(smem + ed * 208))[15 + cc] = f2bf(val);
      }
    }
    // zeros: cols 91..98 (96..98 are pad, harmless)
    {
      int ed = tid >> 3, c8 = tid & 7;
      ((unsigned short*)(smem + ed * 208))[91 + c8] = 0;
    }
  }
  __syncthreads();

  // ---- GEMM1 (transposed): D[n][e] = W1_feat^T x edge_in^T, K=96 ----
  int w    = tid >> 6, lane = tid & 63;
  int c0   = w * 2;                 // 2 n-tiles per wave
  int lr   = lane & 15;             // edge within e-tile
  int quad = lane >> 4, qoff = quad * 16;
  f32x4 acc[8];                     // [c*4 + etile]
  #pragma unroll
  for (int i = 0; i < 8; ++i) acc[i] = (f32x4){0.f, 0.f, 0.f, 0.f};
  const short8* w1f8 = (const short8*)w1f;

  #pragma unroll
  for (int s = 0; s < 3; ++s){
    short8 a0 = w1f8[(s * 16 + c0 + 0) * 64 + lane];
    short8 a1 = w1f8[(s * 16 + c0 + 1) * 64 + lane];
    short8 be0 = *(const short8*)(smem + ( 0 + lr) * 208 + s * 64 + qoff);
    short8 be1 = *(const short8*)(smem + (16 + lr) * 208 + s * 64 + qoff);
    short8 be2 = *(const short8*)(smem + (32 + lr) * 208 + s * 64 + qoff);
    short8 be3 = *(const short8*)(smem + (48 + lr) * 208 + s * 64 + qoff);
    acc[0] = __builtin_amdgcn_mfma_f32_16x16x32_bf16(a0, be0, acc[0], 0, 0, 0);
    acc[1] = __builtin_amdgcn_mfma_f32_16x16x32_bf16(a0, be1, acc[1], 0, 0, 0);
    acc[2] = __builtin_amdgcn_mfma_f32_16x16x32_bf16(a0, be2, acc[2], 0, 0, 0);
    acc[3] = __builtin_amdgcn_mfma_f32_16x16x32_bf16(a0, be3, acc[3], 0, 0, 0);
    acc[4] = __builtin_amdgcn_mfma_f32_16x16x32_bf16(a1, be0, acc[4], 0, 0, 0);
    acc[5] = __builtin_amdgcn_mfma_f32_16x16x32_bf16(a1, be1, acc[5], 0, 0, 0);
    acc[6] = __builtin_amdgcn_mfma_f32_16x16x32_bf16(a1, be2, acc[6], 0, 0, 0);
    acc[7] = __builtin_amdgcn_mfma_f32_16x16x32_bf16(a1, be3, acc[7], 0, 0, 0);
  }
  __syncthreads();   // edge_in reads done; alias LDS as H (64 x 280 bf16)

  // H[e][n] = gelu(D + PROJ_S[src][n] + PROJ_D[dst][n])   (b1 inside PROJ_S)
  {
    char* Hb = smem;
    #pragma unroll
    for (int c = 0; c < 2; ++c){
      int n = (c0 + c) * 16 + quad * 4;
      f32x4 pv[4], qv[4];
      #pragma unroll
      for (int t = 0; t < 4; ++t){
        pv[t] = *(const f32x4*)(ps + (size_t)lsrc[t * 16 + lr] * 256 + n);
        qv[t] = *(const f32x4*)(pd + (size_t)ldst[t * 16 + lr] * 256 + n);
      }
      #pragma unroll
      for (int t = 0; t < 4; ++t){
        int e = t * 16 + lr;
        f32x4 s4 = acc[c * 4 + t];
        float v0 = gelu_s(s4[0] + pv[t][0] + qv[t][0]);
        float v1 = gelu_s(s4[1] + pv[t][1] + qv[t][1]);
        float v2 = gelu_s(s4[2] + pv[t][2] + qv[t][2]);
        float v3 = gelu_s(s4[3] + pv[t][3] + qv[t][3]);
        uint2 p; p.x = pack_bf16(v0, v1); p.y = pack_bf16(v2, v3);
        *(uint2*)(Hb + e * 560 + n * 2) = p;
      }
    }
  }
  __syncthreads();

  // ---- GEMM2 (transposed): wave owns n-tiles {c2,c2+1} x e-tiles {eb,eb+16}
  int c2 = (w & 3) * 2;
  int eb = (w >> 2) * 32;
  f32x4 acc2[4];                    // [c*2 + t]
  #pragma unroll
  for (int i = 0; i < 4; ++i) acc2[i] = (f32x4){0.f, 0.f, 0.f, 0.f};
  const short8* w2f8 = (const short8*)w2f;
  #pragma unroll
  for (int s = 0; s < 8; ++s){
    short8 aa0 = w2f8[(s * 8 + c2 + 0) * 64 + lane];
    short8 aa1 = w2f8[(s * 8 + c2 + 1) * 64 + lane];
    short8 h0 = *(const short8*)(smem + (eb +  0 + lr) * 560 + s * 64 + qoff);
    short8 h1 = *(const short8*)(smem + (eb + 16 + lr) * 560 + s * 64 + qoff);
    acc2[0] = __builtin_amdgcn_mfma_f32_16x16x32_bf16(aa0, h0, acc2[0], 0, 0, 0);
    acc2[1] = __builtin_amdgcn_mfma_f32_16x16x32_bf16(aa0, h1, acc2[1], 0, 0, 0);
    acc2[2] = __builtin_amdgcn_mfma_f32_16x16x32_bf16(aa1, h0, acc2[2], 0, 0, 0);
    acc2[3] = __builtin_amdgcn_mfma_f32_16x16x32_bf16(aa1, h1, acc2[3], 0, 0, 0);
  }

  // output: lane writes 2 x f32x4 per edge (n0, n0+16) -> wave covers full
  // 128-B line of each of its 32 edge rows
  {
    int n0 = c2 * 16 + quad * 4;
    f32x4 bz0 = *(const f32x4*)(bias2 + n0);
    f32x4 bz1 = *(const f32x4*)(bias2 + n0 + 16);
    float* og = outp + (size_t)e0 * 128;
    #pragma unroll
    for (int t = 0; t < 2; ++t){
      int e = eb + t * 16 + lr;
      f32x4 v0, v1;
      v0[0] = acc2[t][0] + bz0[0]; v0[1] = acc2[t][1] + bz0[1];
      v0[2] = acc2[t][2] + bz0[2]; v0[3] = acc2[t][3] + bz0[3];
      v1[0] = acc2[2 + t][0] + bz1[0]; v1[1] = acc2[2 + t][1] + bz1[1];
      v1[2] = acc2[2 + t][2] + bz1[2]; v1[3] = acc2[2 + t][3] + bz1[3];
      *(f32x4*)(og + (size_t)e * 128 + n0)      = v0;
      *(f32x4*)(og + (size_t)e * 128 + n0 + 16) = v1;
    }
  }
}

extern "C" void kernel_launch(void* const* d_in, const int* in_sizes, int n_in,
                              void* d_out, int out_size, void* d_ws, size_t ws_size,
                              hipStream_t stream) {
  const float* emb    = (const float*)d_in[0];
  const float* ts     = (const float*)d_in[1];
  const float* coords = (const float*)d_in[2];
  const float* tf     = (const float*)d_in[3];
  const float* cf     = (const float*)d_in[4];
  const float* w1r    = (const float*)d_in[5];
  const float* b1r    = (const float*)d_in[6];
  const float* w2r    = (const float*)d_in[7];
  const float* b2r    = (const float*)d_in[8];
  const float* wg     = (const float*)d_in[9];
  const float* w1e    = (const float*)d_in[10];
  const float* b1e    = (const float*)d_in[11];
  const float* w2e    = (const float*)d_in[12];
  const float* b2e    = (const float*)d_in[13];
  const int* resi     = (const int*)d_in[14];
  const int* chain    = (const int*)d_in[15];
  const int* gia      = (const int*)d_in[16];
  const int* gib      = (const int*)d_in[17];
  const int* pid      = (const int*)d_in[18];

  char* ws = (char*)d_ws;
  float* RT            = (float*)(ws + WS_RT);
  unsigned short* REPB = (unsigned short*)(ws + WS_REPB);
  unsigned short* W1F  = (unsigned short*)(ws + WS_W1F);
  unsigned short* W2F  = (unsigned short*)(ws + WS_W2F);
  float* PS            = (float*)(ws + WS_PS);
  float* PD            = (float*)(ws + WS_PD);
  unsigned short* W1RF = (unsigned short*)(ws + WS_W1RF);
  unsigned short* W2RF = (unsigned short*)(ws + WS_W2RF);
  float* outp          = (float*)d_out;

  hipLaunchKernelGGL(prep_k, dim3(176), dim3(256), 0, stream,
                     coords, RT, wg, w1e, W1F, w2e, W2F, w1r, W1RF, w2r, W2RF);
  hipLaunchKernelGGL(mlp_k, dim3(32), dim3(512), 0, stream,
                     emb, ts, tf, W1RF, b1r, W2RF, b2r, REPB);
  hipLaunchKernelGGL(proj_k, dim3(32), dim3(512), 0, stream,
                     REPB, W1F, b1e, PS, PD);
  hipLaunchKernelGGL(edge_k, dim3(2080), dim3(512), 0, stream,
                     RT, cf, resi, chain, gia, gib, pid, W1F, W2F, PS, PD,
                     b2e, outp);
}

// Round 13
// 182.017 us; speedup vs baseline: 1.4040x; 1.0584x over previous
//
#include <hip/hip_runtime.h>

// BindingFormer fused pipeline for MI355X (gfx950), round 14b (byte-identical
// resubmit of r14 — container failed twice, infra; OOB re-audit of node_k
// fusion paths found nothing: X<=9392/9472, H1/REP<=8191/8192, w1f tiles
// <=303/304, PS/PD writes end exactly at table end).
// r13: total 192.6 (best), edge 72.0 (r8 body confirmed optimal of 8
// variants), absmax 0.0195. X=120us: ~21 harness memsets/iter (fixed) +
// prep + mlp + proj + 3 gaps. mlp_k/proj_k are serial 32-block launches
// chained through global REPB whose ONLY consumer is proj_k. r14: fuse into
// node_k (64 blk x 512 thr, 16 nodes each): MLP -> REP stays in LDS
// (512B-stride + XOR swz, verified pattern) -> PS/PD GEMMs in-block.
// -1 launch, -REPB round-trip, 2x CU coverage. prep_k/edge_k unchanged.

typedef __attribute__((ext_vector_type(8))) short short8;  // 8 x bf16 (4 VGPRs)
typedef __attribute__((ext_vector_type(4))) float f32x4;   // MFMA accumulator

#define TWO_PI 6.283185307179586f
#define E_AB_TOT 131072

// ws layout (bytes)
#define WS_RT    0         // frames: 1024 x 12 f32            = 49152
#define WS_W1F   573440    // swizzled W1' 19*16*64*8 bf16     = 311296
#define WS_W2F   884736    // swizzled W2  8*8*64*8 bf16       = 65536
#define WS_PS    950272    // PROJ_S f32 1024x256 (+bias1)     = 1048576
#define WS_PD    1998848   // PROJ_D f32 1024x256              = 1048576
#define WS_W1RF  3047424   // swizzled W1_rep 9*16*64*8 bf16   = 147456
#define WS_W2RF  3194880   // swizzled W2_rep 8*16*64*8 bf16   = 131072

__device__ __forceinline__ unsigned short f2bf(float x){
  unsigned int u = __float_as_uint(x);
  u += 0x7fffu + ((u >> 16) & 1u);            // RTNE
  return (unsigned short)(u >> 16);
}

// pack two f32 -> two bf16 (RTNE) in one u32 via v_perm
__device__ __forceinline__ unsigned int pack_bf16(float lo, float hi){
  unsigned int ul = __float_as_uint(lo), uh = __float_as_uint(hi);
  ul += 0x7fffu + ((ul >> 16) & 1u);
  uh += 0x7fffu + ((uh >> 16) & 1u);
  return __builtin_amdgcn_perm(uh, ul, 0x07060302);  // {uh[31:16], ul[31:16]}
}

// gelu tanh-form == x * sigmoid(2z), z = 0.79788456(x + 0.044715 x^3)
__device__ __forceinline__ float gelu_s(float x){
  float s = x * x;
  float w = x * __builtin_fmaf(-0.1029437f, s, -2.30220847f);
  float e = __builtin_exp2f(w);
  return x * __builtin_amdgcn_rcpf(1.0f + e);
}

// ---------- prep: frames (0-3) | swz2 (4-19) | swz1 s>=1 (20-91) |
//            wg1+s0 (92-107) | swz w1r (108-143) | swz w2r (144-175) --------
__global__ __launch_bounds__(256) void prep_k(
    const float* __restrict__ coords, float* __restrict__ RT,
    const float* __restrict__ wg, const float* __restrict__ w1e,
    unsigned short* __restrict__ w1f,
    const float* __restrict__ w2e, unsigned short* __restrict__ w2f,
    const float* __restrict__ w1r, unsigned short* __restrict__ w1rf,
    const float* __restrict__ w2r, unsigned short* __restrict__ w2rf){
  __shared__ float xt[288 * 12];   // wg1 blocks: 128x16 input slab
  __shared__ float ht[256 * 12];   // wg1 blocks: 27x16 result
  int blk = blockIdx.x, tid = threadIdx.x;
  if (blk < 4){                     // ---- frames ----
    int n = blk * 256 + tid;
    const float* p = coords + n * 9;
    float ax=p[0],ay=p[1],az=p[2], bx=p[3],by=p[4],bz=p[5], cx=p[6],cy=p[7],cz=p[8];
    float v1x=cx-bx, v1y=cy-by, v1z=cz-bz;
    float v2x=ax-bx, v2y=ay-by, v2z=az-bz;
    float n1 = sqrtf(v1x*v1x+v1y*v1y+v1z*v1z) + 1e-6f;
    float e1x=v1x/n1, e1y=v1y/n1, e1z=v1z/n1;
    float dp = e1x*v2x + e1y*v2y + e1z*v2z;
    float u2x=v2x-e1x*dp, u2y=v2y-e1y*dp, u2z=v2z-e1z*dp;
    float n2 = sqrtf(u2x*u2x+u2y*u2y+u2z*u2z) + 1e-6f;
    float e2x=u2x/n2, e2y=u2y/n2, e2z=u2z/n2;
    float* r = RT + n * 12;
    r[0]=e1x; r[1]=e2x; r[2]=e1y*e2z - e1z*e2y;
    r[3]=e1y; r[4]=e2y; r[5]=e1z*e2x - e1x*e2z;
    r[6]=e1z; r[7]=e2z; r[8]=e1x*e2y - e1y*e2x;
    r[9]=bx;  r[10]=by; r[11]=bz;
  } else if (blk < 20){             // ---- swz2: W2 edge (256x128) -> frag ----
    int u = (blk - 4) * 4 + (tid >> 6);     // 0..63
    int lane = tid & 63;
    int s = u >> 3, c = u & 7;
    int n  = c * 16 + (lane & 15);
    int kb = s * 32 + (lane >> 4) * 8;
    unsigned short* o = w2f + (((s * 8 + c) * 64) + lane) * 8;
    unsigned short vals[8];
    #pragma unroll
    for (int j = 0; j < 8; ++j)
      vals[j] = f2bf(w2e[(kb + j) * 128 + n]);
    *(uint4*)o = *(const uint4*)vals;
  } else if (blk < 92){             // ---- swz1: W1' edge k-tiles s>=1 ----
    // K: [0:27 geom (wg1 blocks) | 27:91 rope (w1e 128:192) | 91:96 zero
    //     | 96:352 rep_src (192:448) | 352:608 rep_dst (448:704)]
    int u = 16 + (blk - 20) * 4 + (tid >> 6);    // 16..303 (s >= 1)
    int lane = tid & 63;
    int s = u >> 4, c = u & 15;
    int n  = c * 16 + (lane & 15);
    int kb = s * 32 + (lane >> 4) * 8;
    unsigned short* o = w1f + (((s * 16 + c) * 64) + lane) * 8;
    unsigned short vals[8];
    for (int j = 0; j < 8; ++j){
      int k = kb + j;            // >= 32 here
      float val;
      if (k < 91)       val = w1e[(128 + k - 27)  * 256 + n];
      else if (k < 96)  val = 0.f;
      else if (k < 352) val = w1e[(192 + k - 96)  * 256 + n];
      else              val = w1e[(448 + k - 352) * 256 + n];
      vals[j] = f2bf(val);
    }
    *(uint4*)o = *(const uint4*)vals;
  } else if (blk < 108){            // ---- wg1 (27x16 window) + w1f s0 tile ----
    int c = blk - 92;               // 0..15 = n-window = s0 tile index
    int n0 = c * 16;
    float* slab = xt;               // 128 x 16 f32 input slab
    float* res  = ht;               // 27 x 16 f32 result
    #pragma unroll
    for (int i = 0; i < 8; ++i){
      int idx = tid + 256 * i;      // idx = r*16 + cc
      slab[idx] = w1e[(idx >> 4) * 256 + n0 + (idx & 15)];
    }
    __syncthreads();
    #pragma unroll
    for (int i = 0; i < 2; ++i){
      int o = tid + 256 * i;        // 432 outputs = 27k x 16n
      if (o < 432){
        int k = o >> 4, cc = o & 15;
        float acc = 0.f;
        for (int j2 = 0; j2 < 128; ++j2)
          acc += wg[k * 128 + j2] * slab[j2 * 16 + cc];
        res[o] = acc;
      }
    }
    __syncthreads();
    if (tid < 64){                  // write w1f s=0 tile c (k<27 geom,
      int lane = tid;               //  k in [27,32) = first 5 rope rows)
      int nn = lane & 15;
      int kb = (lane >> 4) * 8;
      unsigned short vals[8];
      #pragma unroll
      for (int j = 0; j < 8; ++j){
        int k = kb + j;
        float val = (k < 27) ? res[k * 16 + nn]
                             : w1e[(128 + k - 27) * 256 + n0 + nn];
        vals[j] = f2bf(val);
      }
      *(uint4*)(w1f + ((c * 64) + lane) * 8) = *(const uint4*)vals;
    }
  } else if (blk < 144){            // ---- swz w1r (288x256) -> frag ----
    int u = (blk - 108) * 4 + (tid >> 6);   // 0..143: s = u>>4 (0..8), c = u&15
    int lane = tid & 63;
    int s = u >> 4, c = u & 15;
    int n  = c * 16 + (lane & 15);
    int kb = s * 32 + (lane >> 4) * 8;
    unsigned short* o = w1rf + (((s * 16 + c) * 64) + lane) * 8;
    unsigned short vals[8];
    #pragma unroll
    for (int j = 0; j < 8; ++j)
      vals[j] = f2bf(w1r[(kb + j) * 256 + n]);
    *(uint4*)o = *(const uint4*)vals;
  } else {                          // ---- swz w2r (256x256) -> frag ----
    int u = (blk - 144) * 4 + (tid >> 6);   // 0..127: s = u>>4 (0..7), c = u&15
    int lane = tid & 63;
    int s = u >> 4, c = u & 15;
    int n  = c * 16 + (lane & 15);
    int kb = s * 32 + (lane >> 4) * 8;
    unsigned short* o = w2rf + (((s * 16 + c) * 64) + lane) * 8;
    unsigned short vals[8];
    #pragma unroll
    for (int j = 0; j < 8; ++j)
      vals[j] = f2bf(w2r[(kb + j) * 256 + n]);
    *(uint4*)o = *(const uint4*)vals;
  }
}

// ---------- node_k: fused node MLP + PROJ_S/PROJ_D. 16 nodes/block, 64 blk.
// X[16 x 288] bf16 (stride 592B, 2-way = free) -> GEMM1 K=288 -> gelu ->
// H1[16 x 256] bf16 (512B + XOR swz) -> GEMM2 K=256 -> +b2+emb -> REP bf16
// in LDS (aliases X; 512B + XOR) -> PS/PD GEMMs (w1f k-tiles 3..18) ->
// global PS (+bias1) / PD. REPB global round-trip eliminated.
__global__ __launch_bounds__(512) void node_k(
    const float* __restrict__ emb, const float* __restrict__ ts,
    const float* __restrict__ tf,
    const unsigned short* __restrict__ w1rf, const float* __restrict__ b1r,
    const unsigned short* __restrict__ w2rf, const float* __restrict__ b2r,
    const unsigned short* __restrict__ w1f, const float* __restrict__ b1e,
    float* __restrict__ ps, float* __restrict__ pd)
{
  __shared__ __align__(16) char X[16 * 592];    // 9472 B; REP aliases [16*512]
  __shared__ __align__(16) char H1[16 * 512];   // 8192 B
  int tid = threadIdx.x;
  int n0g = blockIdx.x * 16;

  // ---- fill X: emb cols 0..255 ----
  #pragma unroll
  for (int i = 0; i < 2; ++i){
    int idx = tid + 512 * i;        // 1024 = 16 rows x 64 col-groups
    int row = idx >> 6, g = idx & 63;
    f32x4 e = *(const f32x4*)(emb + (n0g + row) * 256 + g * 4);
    uint2 p; p.x = pack_bf16(e[0], e[1]); p.y = pack_bf16(e[2], e[3]);
    *(uint2*)(X + row * 592 + g * 8) = p;
  }
  if (tid < 256){                   // te cols 256..287: sin at 256+j, cos 272+j
    int nd = tid >> 4, j = tid & 15;
    float ang = TWO_PI * ts[n0g + nd] * tf[j];
    float s, c; __sincosf(ang, &s, &c);
    *(unsigned short*)(X + nd * 592 + 512 + 2 * j) = f2bf(s);
    *(unsigned short*)(X + nd * 592 + 544 + 2 * j) = f2bf(c);
  }
  __syncthreads();

  int w = tid >> 6, lane = tid & 63;
  int c0 = w * 2, lr = lane & 15, quad = lane >> 4, qoff = quad * 16;
  int hx = (lr & 7) << 4;

  // ---- MLP GEMM1: D[n][node] = W1r^T x X^T, K=288 (9 k-tiles) ----
  f32x4 acc[2];
  acc[0] = (f32x4){0.f,0.f,0.f,0.f}; acc[1] = (f32x4){0.f,0.f,0.f,0.f};
  const short8* w1rf8 = (const short8*)w1rf;
  #pragma unroll
  for (int s = 0; s < 9; ++s){
    short8 a0 = w1rf8[(s * 16 + c0 + 0) * 64 + lane];
    short8 a1 = w1rf8[(s * 16 + c0 + 1) * 64 + lane];
    short8 b  = *(const short8*)(X + lr * 592 + s * 64 + qoff);
    acc[0] = __builtin_amdgcn_mfma_f32_16x16x32_bf16(a0, b, acc[0], 0, 0, 0);
    acc[1] = __builtin_amdgcn_mfma_f32_16x16x32_bf16(a1, b, acc[1], 0, 0, 0);
  }
  // H1[node][n] = gelu(D + b1r[n])
  #pragma unroll
  for (int c = 0; c < 2; ++c){
    int n = (c0 + c) * 16 + quad * 4;
    f32x4 bz = *(const f32x4*)(b1r + n);
    f32x4 s4 = acc[c];
    float v0 = gelu_s(s4[0] + bz[0]);
    float v1 = gelu_s(s4[1] + bz[1]);
    float v2 = gelu_s(s4[2] + bz[2]);
    float v3 = gelu_s(s4[3] + bz[3]);
    uint2 p; p.x = pack_bf16(v0, v1); p.y = pack_bf16(v2, v3);
    *(uint2*)(H1 + ((lr * 512 + n * 2) ^ hx)) = p;
  }
  __syncthreads();

  // ---- MLP GEMM2: D[n][node] = W2r^T x H1^T, K=256 (8 k-tiles) ----
  f32x4 acc2[2];
  acc2[0] = (f32x4){0.f,0.f,0.f,0.f}; acc2[1] = (f32x4){0.f,0.f,0.f,0.f};
  const short8* w2rf8 = (const short8*)w2rf;
  #pragma unroll
  for (int s = 0; s < 8; ++s){
    short8 a0 = w2rf8[(s * 16 + c0 + 0) * 64 + lane];
    short8 a1 = w2rf8[(s * 16 + c0 + 1) * 64 + lane];
    short8 b  = *(const short8*)(H1 + ((lr * 512 + s * 64 + qoff) ^ hx));
    acc2[0] = __builtin_amdgcn_mfma_f32_16x16x32_bf16(a0, b, acc2[0], 0, 0, 0);
    acc2[1] = __builtin_amdgcn_mfma_f32_16x16x32_bf16(a1, b, acc2[1], 0, 0, 0);
  }
  // REP[node][n] = bf16(D + b2r[n] + emb[node][n])  (REP aliases X; X dead)
  char* REP = X;
  #pragma unroll
  for (int c = 0; c < 2; ++c){
    int n = (c0 + c) * 16 + quad * 4;
    f32x4 bz = *(const f32x4*)(b2r + n);
    f32x4 e = *(const f32x4*)(emb + (n0g + lr) * 256 + n);
    f32x4 s4 = acc2[c];
    uint2 p;
    p.x = pack_bf16(s4[0] + bz[0] + e[0], s4[1] + bz[1] + e[1]);
    p.y = pack_bf16(s4[2] + bz[2] + e[2], s4[3] + bz[3] + e[3]);
    *(uint2*)(REP + ((lr * 512 + n * 2) ^ hx)) = p;
  }
  __syncthreads();

  // ---- PROJ: PS = REP @ W1_src (+b1e), PD = REP @ W1_dst; K=256 ----
  f32x4 accS[2], accD[2];
  accS[0] = (f32x4){0.f,0.f,0.f,0.f}; accS[1] = (f32x4){0.f,0.f,0.f,0.f};
  accD[0] = (f32x4){0.f,0.f,0.f,0.f}; accD[1] = (f32x4){0.f,0.f,0.f,0.f};
  const short8* w1f8 = (const short8*)w1f;
  #pragma unroll
  for (int s = 0; s < 8; ++s){
    short8 aS0 = w1f8[((3 + s) * 16 + c0 + 0) * 64 + lane];
    short8 aS1 = w1f8[((3 + s) * 16 + c0 + 1) * 64 + lane];
    short8 aD0 = w1f8[((11 + s) * 16 + c0 + 0) * 64 + lane];
    short8 aD1 = w1f8[((11 + s) * 16 + c0 + 1) * 64 + lane];
    short8 b   = *(const short8*)(REP + ((lr * 512 + s * 64 + qoff) ^ hx));
    accS[0] = __builtin_amdgcn_mfma_f32_16x16x32_bf16(aS0, b, accS[0], 0, 0, 0);
    accS[1] = __builtin_amdgcn_mfma_f32_16x16x32_bf16(aS1, b, accS[1], 0, 0, 0);
    accD[0] = __builtin_amdgcn_mfma_f32_16x16x32_bf16(aD0, b, accD[0], 0, 0, 0);
    accD[1] = __builtin_amdgcn_mfma_f32_16x16x32_bf16(aD1, b, accD[1], 0, 0, 0);
  }
  #pragma unroll
  for (int c = 0; c < 2; ++c){
    int n = (c0 + c) * 16 + quad * 4;
    f32x4 bz = *(const f32x4*)(b1e + n);
    f32x4 vS = accS[c], vD = accD[c];
    vS[0] += bz[0]; vS[1] += bz[1]; vS[2] += bz[2]; vS[3] += bz[3];
    *(f32x4*)(ps + (size_t)(n0g + lr) * 256 + n) = vS;
    *(f32x4*)(pd + (size_t)(n0g + lr) * 256 + n) = vD;
  }
}

// ---------- fused edge kernel (r8 body verbatim: 72.0us measured) ----------
// 64 edges/block, 512 thr; H stride 560 (conflict-free); plain PROJ gathers
// in the H epilogue; LDS 43008 -> 3 blocks/CU (clean-write regime).
__global__ __launch_bounds__(512, 4) void edge_k(
    const float* __restrict__ RT,  const float* __restrict__ cf,
    const int* __restrict__ resi, const int* __restrict__ chain,
    const int* __restrict__ gia,  const int* __restrict__ gib,
    const int* __restrict__ pid,
    const unsigned short* __restrict__ w1f, const unsigned short* __restrict__ w2f,
    const float* __restrict__ ps, const float* __restrict__ pd,
    const float* __restrict__ bias2,
    float* __restrict__ outp)
{
  // phase1: edge_in 64 x 208 B (96 bf16 + pad); phase2 alias: H 64 x 560 B
  __shared__ __align__(16) char smem[35840];
  __shared__ __align__(16) float rtbuf[128][12];   // 64 src rows, 64 dst rows
  __shared__ float scD[64];                         // disp
  __shared__ float scI[64];                         // rope scale (chain mask)
  __shared__ int lsrc[64];
  __shared__ int ldst[64];

  int tid = threadIdx.x;
  int e0  = blockIdx.x * 64;

  if (tid < 64){                    // indices + per-edge scalars
    int e = e0 + tid, s_, d_;
    if (e < E_AB_TOT){ s_ = gia[e]; d_ = gib[e]; }
    else {
      int i = e - E_AB_TOT;
      int b = i >> 10, w_ = i & 1023;
      s_ = pid[b * 32 + (w_ >> 5)];
      d_ = pid[b * 32 + (w_ & 31)];
    }
    lsrc[tid] = s_; ldst[tid] = d_;
    float disp = ((float)resi[s_] - (float)resi[d_]) * 0.125f;
    scD[tid] = disp;
    scI[tid] = (chain[s_] == chain[d_]) ? 1.f / (fabsf(disp) + 1.f) : 0.f;
  } else if (tid < 192){            // RT staging: 128 rows x 48 B, vectorized
    int r  = tid - 64;              // 0..127 : 0..63 = src rows, 64..127 = dst
    int e  = e0 + (r & 63);
    int node;
    if (e < E_AB_TOT){ node = (r < 64) ? gia[e] : gib[e]; }
    else {
      int i = e - E_AB_TOT;
      int b = i >> 10, w_ = i & 1023;
      node = (r < 64) ? pid[b * 32 + (w_ >> 5)] : pid[b * 32 + (w_ & 31)];
    }
    const f32x4* p = (const f32x4*)(RT + node * 12);
    f32x4* q = (f32x4*)(&rtbuf[r][0]);
    q[0] = p[0]; q[1] = p[1]; q[2] = p[2];
  }
  __syncthreads();

  // ---- divergence-free feature fill (cols 0..95 of edge_in) ----
  {
    // rope: 2048 (edge, freq) pairs, one sincos fills sin+cos cols
    #pragma unroll
    for (int it = 0; it < 4; ++it){
      int v = it * 512 + tid, ed = v >> 5, j = v & 31;
      float ang = TWO_PI * scD[ed] * cf[j];
      float s, c; __sincosf(ang, &s, &c);
      float inv = scI[ed];
      unsigned short* row = (unsigned short*)(smem + ed * 208);
      row[27 + j] = f2bf(s * inv);
      row[59 + j] = f2bf(c * inv);
    }
    // rbf: 64 edges x 15 centers (c==15 lanes idle)
    #pragma unroll
    for (int it = 0; it < 2; ++it){
      int v = it * 512 + tid, ed = v >> 4, c = v & 15;
      float tx = rtbuf[64 + ed][9]  - rtbuf[ed][9];
      float ty = rtbuf[64 + ed][10] - rtbuf[ed][10];
      float tz = rtbuf[64 + ed][11] - rtbuf[ed][11];
      float dist = sqrtf(tx*tx + ty*ty + tz*tz + 1e-6f);
      if (c < 15){
        float z = (dist - (float)c * (20.f / 14.f)) * (15.f / 20.f);
        ((unsigned short*)(smem + ed * 208))[c] = f2bf(__expf(-0.5f * z * z));
      }
    }
    // relrot (9) + local (3): cols 15..26
    #pragma unroll
    for (int it = 0; it < 2; ++it){
      int v = it * 512 + tid, ed = v >> 4, cc = v & 15;
      if (cc < 12){
        const float* Rs = &rtbuf[ed][0];
        const float* Rd = &rtbuf[64 + ed][0];
        float val;
        if (cc < 9){
          int a  = (cc >= 6) ? 2 : ((cc >= 3) ? 1 : 0);
          int b_ = cc - 3 * a;
          val = Rs[a]*Rd[b_] + Rs[3+a]*Rd[3+b_] + Rs[6+a]*Rd[6+b_];
        } else {
          int k = cc - 9;
          float tx = Rd[9]-Rs[9], ty = Rd[10]-Rs[10], tz = Rd[11]-Rs[11];
          float dist = sqrtf(tx*tx + ty*ty + tz*tz + 1e-6f);
          val = (Rs[k]*tx + Rs[3+k]*ty + Rs[6+k]*tz) / (dist + 1.f);
        }
        ((unsigned short*)(smem + ed * 208))[15 + cc] = f2bf(val);
      }
    }
    // zeros: cols 91..98 (96..98 are pad, harmless)
    {
      int ed = tid >> 3, c8 = tid & 7;
      ((unsigned short*)(smem + ed * 208))[91 + c8] = 0;
    }
  }
  __syncthreads();

  // ---- GEMM1 (transposed): D[n][e] = W1_feat^T x edge_in^T, K=96 ----
  int w    = tid >> 6, lane = tid & 63;
  int c0   = w * 2;                 // 2 n-tiles per wave
  int lr   = lane & 15;             // edge within e-tile
  int quad = lane >> 4, qoff = quad * 16;
  f32x4 acc[8];                     // [c*4 + etile]
  #pragma unroll
  for (int i = 0; i < 8; ++i) acc[i] = (f32x4){0.f, 0.f, 0.f, 0.f};
  const short8* w1f8 = (const short8*)w1f;

  #pragma unroll
  for (int s = 0; s < 3; ++s){
    short8 a0 = w1f8[(s * 16 + c0 + 0) * 64 + lane];
    short8 a1 = w1f8[(s * 16 + c0 + 1) * 64 + lane];
    short8 be0 = *(const short8*)(smem + ( 0 + lr) * 208 + s * 64 + qoff);
    short8 be1 = *(const short8*)(smem + (16 + lr) * 208 + s * 64 + qoff);
    short8 be2 = *(const short8*)(smem + (32 + lr) * 208 + s * 64 + qoff);
    short8 be3 = *(const short8*)(smem + (48 + lr) * 208 + s * 64 + qoff);
    acc[0] = __builtin_amdgcn_mfma_f32_16x16x32_bf16(a0, be0, acc[0], 0, 0, 0);
    acc[1] = __builtin_amdgcn_mfma_f32_16x16x32_bf16(a0, be1, acc[1], 0, 0, 0);
    acc[2] = __builtin_amdgcn_mfma_f32_16x16x32_bf16(a0, be2, acc[2], 0, 0, 0);
    acc[3] = __builtin_amdgcn_mfma_f32_16x16x32_bf16(a0, be3, acc[3], 0, 0, 0);
    acc[4] = __builtin_amdgcn_mfma_f32_16x16x32_bf16(a1, be0, acc[4], 0, 0, 0);
    acc[5] = __builtin_amdgcn_mfma_f32_16x16x32_bf16(a1, be1, acc[5], 0, 0, 0);
    acc[6] = __builtin_amdgcn_mfma_f32_16x16x32_bf16(a1, be2, acc[6], 0, 0, 0);
    acc[7] = __builtin_amdgcn_mfma_f32_16x16x32_bf16(a1, be3, acc[7], 0, 0, 0);
  }
  __syncthreads();   // edge_in reads done; alias LDS as H (64 x 280 bf16)

  // H[e][n] = gelu(D + PROJ_S[src][n] + PROJ_D[dst][n])   (b1 inside PROJ_S)
  {
    char* Hb = smem;
    #pragma unroll
    for (int c = 0; c < 2; ++c){
      int n = (c0 + c) * 16 + quad * 4;
      f32x4 pv[4], qv[4];
      #pragma unroll
      for (int t = 0; t < 4; ++t){
        pv[t] = *(const f32x4*)(ps + (size_t)lsrc[t * 16 + lr] * 256 + n);
        qv[t] = *(const f32x4*)(pd + (size_t)ldst[t * 16 + lr] * 256 + n);
      }
      #pragma unroll
      for (int t = 0; t < 4; ++t){
        int e = t * 16 + lr;
        f32x4 s4 = acc[c * 4 + t];
        float v0 = gelu_s(s4[0] + pv[t][0] + qv[t][0]);
        float v1 = gelu_s(s4[1] + pv[t][1] + qv[t][1]);
        float v2 = gelu_s(s4[2] + pv[t][2] + qv[t][2]);
        float v3 = gelu_s(s4[3] + pv[t][3] + qv[t][3]);
        uint2 p; p.x = pack_bf16(v0, v1); p.y = pack_bf16(v2, v3);
        *(uint2*)(Hb + e * 560 + n * 2) = p;
      }
    }
  }
  __syncthreads();

  // ---- GEMM2 (transposed): wave owns n-tiles {c2,c2+1} x e-tiles {eb,eb+16}
  int c2 = (w & 3) * 2;
  int eb = (w >> 2) * 32;
  f32x4 acc2[4];                    // [c*2 + t]
  #pragma unroll
  for (int i = 0; i < 4; ++i) acc2[i] = (f32x4){0.f, 0.f, 0.f, 0.f};
  const short8* w2f8 = (const short8*)w2f;
  #pragma unroll
  for (int s = 0; s < 8; ++s){
    short8 aa0 = w2f8[(s * 8 + c2 + 0) * 64 + lane];
    short8 aa1 = w2f8[(s * 8 + c2 + 1) * 64 + lane];
    short8 h0 = *(const short8*)(smem + (eb +  0 + lr) * 560 + s * 64 + qoff);
    short8 h1 = *(const short8*)(smem + (eb + 16 + lr) * 560 + s * 64 + qoff);
    acc2[0] = __builtin_amdgcn_mfma_f32_16x16x32_bf16(aa0, h0, acc2[0], 0, 0, 0);
    acc2[1] = __builtin_amdgcn_mfma_f32_16x16x32_bf16(aa0, h1, acc2[1], 0, 0, 0);
    acc2[2] = __builtin_amdgcn_mfma_f32_16x16x32_bf16(aa1, h0, acc2[2], 0, 0, 0);
    acc2[3] = __builtin_amdgcn_mfma_f32_16x16x32_bf16(aa1, h1, acc2[3], 0, 0, 0);
  }

  // output: lane writes 2 x f32x4 per edge (n0, n0+16) -> wave covers full
  // 128-B line of each of its 32 edge rows
  {
    int n0 = c2 * 16 + quad * 4;
    f32x4 bz0 = *(const f32x4*)(bias2 + n0);
    f32x4 bz1 = *(const f32x4*)(bias2 + n0 + 16);
    float* og = outp + (size_t)e0 * 128;
    #pragma unroll
    for (int t = 0; t < 2; ++t){
      int e = eb + t * 16 + lr;
      f32x4 v0, v1;
      v0[0] = acc2[t][0] + bz0[0]; v0[1] = acc2[t][1] + bz0[1];
      v0[2] = acc2[t][2] + bz0[2]; v0[3] = acc2[t][3] + bz0[3];
      v1[0] = acc2[2 + t][0] + bz1[0]; v1[1] = acc2[2 + t][1] + bz1[1];
      v1[2] = acc2[2 + t][2] + bz1[2]; v1[3] = acc2[2 + t][3] + bz1[3];
      *(f32x4*)(og + (size_t)e * 128 + n0)      = v0;
      *(f32x4*)(og + (size_t)e * 128 + n0 + 16) = v1;
    }
  }
}

extern "C" void kernel_launch(void* const* d_in, const int* in_sizes, int n_in,
                              void* d_out, int out_size, void* d_ws, size_t ws_size,
                              hipStream_t stream) {
  const float* emb    = (const float*)d_in[0];
  const float* ts     = (const float*)d_in[1];
  const float* coords = (const float*)d_in[2];
  const float* tf     = (const float*)d_in[3];
  const float* cf     = (const float*)d_in[4];
  const float* w1r    = (const float*)d_in[5];
  const float* b1r    = (const float*)d_in[6];
  const float* w2r    = (const float*)d_in[7];
  const float* b2r    = (const float*)d_in[8];
  const float* wg     = (const float*)d_in[9];
  const float* w1e    = (const float*)d_in[10];
  const float* b1e    = (const float*)d_in[11];
  const float* w2e    = (const float*)d_in[12];
  const float* b2e    = (const float*)d_in[13];
  const int* resi     = (const int*)d_in[14];
  const int* chain    = (const int*)d_in[15];
  const int* gia      = (const int*)d_in[16];
  const int* gib      = (const int*)d_in[17];
  const int* pid      = (const int*)d_in[18];

  char* ws = (char*)d_ws;
  float* RT            = (float*)(ws + WS_RT);
  unsigned short* W1F  = (unsigned short*)(ws + WS_W1F);
  unsigned short* W2F  = (unsigned short*)(ws + WS_W2F);
  float* PS            = (float*)(ws + WS_PS);
  float* PD            = (float*)(ws + WS_PD);
  unsigned short* W1RF = (unsigned short*)(ws + WS_W1RF);
  unsigned short* W2RF = (unsigned short*)(ws + WS_W2RF);
  float* outp          = (float*)d_out;

  hipLaunchKernelGGL(prep_k, dim3(176), dim3(256), 0, stream,
                     coords, RT, wg, w1e, W1F, w2e, W2F, w1r, W1RF, w2r, W2RF);
  hipLaunchKernelGGL(node_k, dim3(64), dim3(512), 0, stream,
                     emb, ts, tf, W1RF, b1r, W2RF, b2r, W1F, b1e, PS, PD);
  hipLaunchKernelGGL(edge_k, dim3(2080), dim3(512), 0, stream,
                     RT, cf, resi, chain, gia, gib, pid, W1F, W2F, PS, PD,
                     b2e, outp);
}